// Round 12
// baseline (9368.652 us; speedup 1.0000x reference)
//
#include <hip/hip_runtime.h>
#include <hip/hip_bf16.h>
#include <hip/hip_fp16.h>

#define NF    15
#define NBF   20
#define TT    1760
#define TS    880
#define EP    64
#define ES    128
#define DF    128
#define H1    384
#define G3    1152
#define INA   896
#define JREP  11

typedef _Float16 h2v __attribute__((ext_vector_type(2)));

__device__ __forceinline__ float sigmf_(float x){ return 1.0f/(1.0f + __expf(-x)); }
__device__ __forceinline__ float tanhf_(float x){ return 2.0f/(1.0f + __expf(-2.0f*x)) - 1.0f; }
__device__ __forceinline__ h2v bc_h2(unsigned u){ return __builtin_bit_cast(h2v, u); }
__device__ __forceinline__ float fdot2_(h2v a, h2v b, float c){
#if __has_builtin(__builtin_amdgcn_fdot2)
  return __builtin_amdgcn_fdot2(a, b, c, false);
#else
  return c + (float)a[0]*(float)b[0] + (float)a[1]*(float)b[1];
#endif
}
__device__ __forceinline__ unsigned pk2_(float a, float b){
#if __has_builtin(__builtin_amdgcn_cvt_pkrtz)
  return __builtin_bit_cast(unsigned, __builtin_amdgcn_cvt_pkrtz(a, b));
#else
  unsigned lo = (unsigned)__builtin_bit_cast(unsigned short, (_Float16)a);
  unsigned hi = (unsigned)__builtin_bit_cast(unsigned short, (_Float16)b);
  return lo | (hi << 16);
#endif
}
__device__ __forceinline__ void bar_lgkm(){
  asm volatile("s_waitcnt lgkmcnt(0)" ::: "memory");
  __builtin_amdgcn_s_barrier();
  __builtin_amdgcn_sched_barrier(0);
}

// ---------------- frame-rate network: f[64][11][128] ----------------
__global__ __launch_bounds__(128) void k_frame(const float* feat, const int* periods, const float* embp,
   const float* c1w, const float* c1b, const float* c2w, const float* c2b,
   const float* f1w, const float* f1b, const float* f2w, const float* f2b, float* fout)
{
  __shared__ float cat[NF*84];
  __shared__ float x1[13*DF];
  __shared__ float x2[JREP*DF];
  int b = blockIdx.x, tid = threadIdx.x;
  for (int idx = tid; idx < NF*84; idx += 128){
    int j = idx/84, c = idx%84;
    cat[idx] = (c < NBF) ? feat[(b*NF+j)*NBF + c]
                         : embp[periods[b*NF+j]*EP + (c-NBF)];
  }
  __syncthreads();
  int o = tid;
  for (int p = 0; p < 13; ++p){
    float acc = c1b[o];
    for (int kk = 0; kk < 3; ++kk)
      for (int c = 0; c < 84; ++c)
        acc += cat[(p+kk)*84 + c] * c1w[(o*84+c)*3+kk];
    x1[p*DF+o] = tanhf_(acc);
  }
  __syncthreads();
  for (int p = 0; p < JREP; ++p){
    float acc = c2b[o];
    for (int kk = 0; kk < 3; ++kk)
      for (int c = 0; c < DF; ++c)
        acc += x1[(p+kk)*DF+c] * c2w[(o*DF+c)*3+kk];
    x2[p*DF+o] = tanhf_(acc);
  }
  __syncthreads();
  for (int p = 0; p < JREP; ++p){
    float acc = f1b[o];
    for (int c = 0; c < DF; ++c) acc += x2[p*DF+c]*f1w[o*DF+c];
    x1[p*DF+o] = tanhf_(acc);
  }
  __syncthreads();
  for (int p = 0; p < JREP; ++p){
    float acc = f2b[o];
    for (int c = 0; c < DF; ++c) acc += x1[p*DF+c]*f2w[o*DF+c];
    fout[(b*JREP+p)*DF+o] = tanhf_(acc);
  }
}

// ---------------- pack ga_whh f32 -> per-(hf,thread) uint4-contiguous f16 (j-quarter split) ------
__global__ __launch_bounds__(256) void k_wpack5(const float* whh, _Float16* wpk){
  int o = blockIdx.x*256 + threadIdx.x;        // < 442368
  int hu = o & 1;
  int c  = (o >> 1) & 3;
  int idx = o >> 3;                            // uint4 index
  int tid = idx % 768;
  int n   = (idx / 768) % 18;
  int hf  = idx / (768*18);
  int i = tid % 384, u = tid / 384;
  int gd = n*4 + c;
  int m = gd / 12, dc = gd % 12;
  int pos  = (dc % 2) + 2*(dc / 6);
  int gate = (dc % 6) >> 1;
  int j = hf*96 + u*48 + (4*m + pos)*2 + hu;
  wpk[o] = (_Float16)whh[(gate*H1 + i)*H1 + j];
}

// ---------------- GA tables: GA[k][256][1152] ----------------
__global__ __launch_bounds__(256) void k_tables(const float* wih, const float* emb, float* GA){
  __shared__ float Wl[64*129];
  int k = blockIdx.x/18, g0 = (blockIdx.x%18)*64;
  int tid = threadIdx.x;
  for (int idx = tid; idx < 64*128; idx += 256){
    int gg = idx>>7, c = idx&127;
    Wl[gg*129+c] = wih[(size_t)(g0+gg)*INA + k*128 + c];
  }
  __syncthreads();
  int vv = tid>>6, gg = tid&63;
  for (int v = vv; v < 256; v += 4){
    const float* e = emb + (size_t)v*ES;
    float acc = 0.f;
    for (int c = 0; c < 128; ++c) acc += e[c]*Wl[gg*129+c];
    GA[(size_t)(k*256+v)*G3 + g0+gg] = acc;
  }
}

// ---------------- xWrepA[b][j][1152] ----------------
__global__ __launch_bounds__(256) void k_xwrepA(const float* wih, const float* f,
                                                const float* bih, const float* bhh, float* xwA){
  __shared__ float Wl[64*129];
  int g0 = blockIdx.x*64, tid = threadIdx.x;
  for (int idx = tid; idx < 64*128; idx += 256){
    int gg = idx>>7, c = idx&127;
    Wl[gg*129+c] = wih[(size_t)(g0+gg)*INA + 768 + c];
  }
  __syncthreads();
  int vv = tid>>6, gg = tid&63; int g = g0+gg;
  float badd = bih[g] + (g < 768 ? bhh[g] : 0.f);
  for (int row = vv; row < 64*JREP; row += 4){
    const float* fr = f + (size_t)row*DF;
    float acc = badd;
    for (int c = 0; c < 128; ++c) acc += fr[c]*Wl[gg*129+c];
    xwA[(size_t)row*G3 + g] = acc;
  }
}

// ---------------- xWrepB[b][j][48] ----------------
__global__ __launch_bounds__(256) void k_xwrepB(const float* wih, const float* f,
                                                const float* bih, const float* bhh, float* xwB){
  __shared__ float Wl[48*129];
  int b = blockIdx.x, tid = threadIdx.x;
  for (int idx = tid; idx < 48*128; idx += 256){
    int r = idx>>7, c = idx&127;
    Wl[r*129+c] = wih[r*512 + 384 + c];
  }
  __syncthreads();
  for (int idx = tid; idx < JREP*48; idx += 256){
    int j = idx/48, r = idx%48;
    const float* fr = f + (size_t)(b*JREP+j)*DF;
    float acc = bih[r] + (r < 32 ? bhh[r] : 0.f);
    for (int c = 0; c < 128; ++c) acc += fr[c]*Wl[r*129+c];
    xwB[(size_t)(b*JREP+j)*48 + r] = acc;
  }
}

// ---------------- md2 embed tables: T2[tbl][256][256] ----------------
__global__ __launch_bounds__(256) void k_t2(const float* w1, const float* w2, const float* emb, float* T2){
  __shared__ float Wl[64*129];
  int tbl = blockIdx.x>>2; int c0 = (blockIdx.x&3)*64; int tid = threadIdx.x;
  const float* w = tbl ? w2 : w1;
  for (int idx = tid; idx < 64*128; idx += 256){
    int cc = idx>>7, e = idx&127;
    Wl[cc*129+e] = w[(c0+cc)*144 + 16 + e];
  }
  __syncthreads();
  int vv = tid>>6, cc = tid&63;
  for (int v = vv; v < 256; v += 4){
    const float* e = emb + (size_t)v*ES;
    float acc = 0.f;
    for (int c = 0; c < 128; ++c) acc += e[c]*Wl[cc*129+c];
    T2[tbl*65536 + v*256 + c0+cc] = acc;
  }
}

// ---------------- GRU-A scan v12: 4-batch multiplex, partial-forwarding (R9 exchange) ----------
#define LD18(n) uint4 d##n = wsrc[(size_t)(n)*768];
#define Q2(A,B,C, q2) { \
  h2v hA = hh[jb2 + (q2)*2],     hB = hh[jb2 + (q2)*2 + 1]; \
  ar = fdot2_(hA, bc_h2(A.x), ar); ar = fdot2_(hB, bc_h2(A.y), ar); \
  az = fdot2_(hA, bc_h2(A.z), az); az = fdot2_(hB, bc_h2(A.w), az); \
  an = fdot2_(hA, bc_h2(B.x), an); an = fdot2_(hB, bc_h2(B.y), an); \
  h2v hC = hh[jb2 + (q2)*2 + 2], hD = hh[jb2 + (q2)*2 + 3]; \
  ar = fdot2_(hC, bc_h2(B.z), ar); ar = fdot2_(hD, bc_h2(B.w), ar); \
  az = fdot2_(hC, bc_h2(C.x), az); az = fdot2_(hD, bc_h2(C.y), az); \
  an = fdot2_(hC, bc_h2(C.z), an); an = fdot2_(hD, bc_h2(C.w), an); }
#define DOTS12 \
  Q2(d0,d1,d2,0) Q2(d3,d4,d5,2) Q2(d6,d7,d8,4) \
  Q2(d9,d10,d11,6) Q2(d12,d13,d14,8) Q2(d15,d16,d17,10)

#define PLW(n, p) { unsigned w = __hip_atomic_load((p), __ATOMIC_RELAXED, __HIP_MEMORY_SCOPE_AGENT); \
                    rv##n = w; ok &= ((w & 1023u) == tg); }

#define PHASE(m) { \
  const int tp = t + 1; \
  float ga0=0.f,ga1=0.f,ga2=0.f,ga3=0.f,ga4=0.f,ga5=0.f,gx0=0.f; \
  float gb0=0.f,gb1=0.f,gb2=0.f,gb3=0.f,gb4=0.f,gb5=0.f,gx1=0.f; \
  if (tp < TS && isGat){ \
    int v0=indr[m][tp&1][0], v1=indr[m][tp&1][1], v2=indr[m][tp&1][2]; \
    int v3=indr[m][tp&1][3], v4=indr[m][tp&1][4], v5=indr[m][tp&1][5]; \
    const float* xwr = xwA + ((size_t)((gq*4+m)*JREP) + tp/80)*G3; \
    ga0 = GA[((size_t)0*256 + v0)*G3 + c0]; gb0 = GA[((size_t)0*256 + v0)*G3 + c1]; \
    ga1 = GA[((size_t)1*256 + v1)*G3 + c0]; gb1 = GA[((size_t)1*256 + v1)*G3 + c1]; \
    ga2 = GA[((size_t)2*256 + v2)*G3 + c0]; gb2 = GA[((size_t)2*256 + v2)*G3 + c1]; \
    ga3 = GA[((size_t)3*256 + v3)*G3 + c0]; gb3 = GA[((size_t)3*256 + v3)*G3 + c1]; \
    ga4 = GA[((size_t)4*256 + v4)*G3 + c0]; gb4 = GA[((size_t)4*256 + v4)*G3 + c1]; \
    ga5 = GA[((size_t)5*256 + v5)*G3 + c0]; gb5 = GA[((size_t)5*256 + v5)*G3 + c1]; \
    gx0 = xwr[c0]; gx1 = xwr[c1]; \
  } \
  int iv = 0; \
  if ((m) == 0 && doStg && (t+2) < TS) \
    iv = in_data[(size_t)(gq*4+stgM)*TT*3 + 6*(t+2) + stgK]; \
  float ar=0.f, az=0.f, an=0.f; \
  { const h2v* hh = (const h2v*)&h16u[m][0]; DOTS12 } \
  pg[m][0][u][i] = ar; pg[m][1][u][i] = az; pg[m][2][u][i] = an; \
  if (tp < TS && isGat){ \
    xwb[m][tp&1][c0] = ga0+ga1+ga2+ga3+ga4+ga5+gx0; \
    xwb[m][tp&1][c1] = gb0+gb1+gb2+gb3+gb4+gb5+gx1; \
  } \
  if ((m) == 0 && doStg && (t+2) < TS) indr[stgM][t&1][stgK] = iv; \
  bar_lgkm(); \
  if (isPub){ \
    int po0 = 2*(tid - 192); int gg = po0/384, ii = po0 - gg*384; \
    float2 p0 = *(const float2*)&pg[m][gg][0][ii]; \
    float2 p1 = *(const float2*)&pg[m][gg][1][ii]; \
    float v0f = p0.x + p1.x, v1f = p0.y + p1.y; \
    unsigned tw0 = (__builtin_bit_cast(unsigned, v0f) & 0xFFFFFC00u) | (unsigned)(t & 1023); \
    unsigned tw1 = (__builtin_bit_cast(unsigned, v1f) & 0xFFFFFC00u) | (unsigned)(t & 1023); \
    unsigned* dst = pbuf + ((size_t)((gq*4+m)*4 + hf)*2 + nb)*G3 + po0; \
    __hip_atomic_store(dst,   tw0, __ATOMIC_RELAXED, __HIP_MEMORY_SCOPE_AGENT); \
    __hip_atomic_store(dst+1, tw1, __ATOMIC_RELAXED, __HIP_MEMORY_SCOPE_AGENT); \
  } \
}

__global__ __launch_bounds__(768, 3) void k_scanA12(const int* __restrict__ in_data,
        const float* __restrict__ GA, const float* __restrict__ xwA,
        const uint4* __restrict__ wpk, const float* __restrict__ bhh,
        unsigned* __restrict__ g1u, unsigned* pbuf)
{
  __shared__ __align__(16) unsigned h16u[4][48];    // per-batch own j-quarter h
  __shared__ __align__(8)  float pg[4][3][2][384];  // per-batch partials
  __shared__ __align__(8)  float xwb[4][2][G3];     // per-batch xW double buffer
  __shared__ int indr[4][2][8];
  const int P = blockIdx.x;
  const int gq = P >> 2, hf = P & 3;     // group (4 batches), j-quarter
  const int tid = threadIdx.x;
  const int i  = tid % 384;
  const int u  = tid / 384;
  const int jb2 = u * 24;

  // weights: 18 uint4 (j-quarter slice), shared by all 4 batches
  const uint4* wsrc = wpk + (size_t)(hf*18)*768 + tid;
  LD18(0) LD18(1) LD18(2) LD18(3) LD18(4) LD18(5) LD18(6) LD18(7) LD18(8)
  LD18(9) LD18(10) LD18(11) LD18(12) LD18(13) LD18(14) LD18(15) LD18(16) LD18(17)

  const bool isGat = (tid < 576);
  const int  c0 = 2*tid, c1 = 2*tid + 1;
  const bool isPub = (tid >= 192);                 // 576 publisher lanes
  const bool doStg = (tid >= 576 && tid < 600);
  const int  stgM = doStg ? (tid-576)/6 : 0;
  const int  stgK = doStg ? (tid-576)%6 : 0;

  // epilogue assignment: wave m (m<4), lanes 0..47 handle batch gq*4+m
  const int meW = tid >> 6;                        // wave
  const int l   = tid & 63;
  const bool isEpi = (meW < 4) && (l < 48);
  float hreg0 = 0.f, hreg1 = 0.f, bn0 = 0.f, bn1 = 0.f;
  size_t g1base = 0;
  const unsigned *eq1 = pbuf, *eq2 = pbuf, *eq3 = pbuf;
  if (isEpi){
    bn0 = bhh[768 + hf*96 + 2*l];
    bn1 = bhh[768 + hf*96 + 2*l + 1];
    int bb = gq*4 + meW;
    g1base = (size_t)bb*TS*192 + hf*48 + l;
    eq1 = pbuf + ((size_t)(bb*4 + ((hf+1)&3))*2)*G3 + hf*96 + 2*l;
    eq2 = pbuf + ((size_t)(bb*4 + ((hf+2)&3))*2)*G3 + hf*96 + 2*l;
    eq3 = pbuf + ((size_t)(bb*4 + ((hf+3)&3))*2)*G3 + hf*96 + 2*l;
  }
  if (tid < 192) ((unsigned*)h16u)[tid] = 0u;

  // prologue: xwb[m][0] for t=0 ; indr[m][1] for t=1
  if (isGat){
    #pragma unroll
    for (int m = 0; m < 4; ++m){
      const int* ib = in_data + (size_t)(gq*4+m)*TT*3;
      float s0 = xwA[(size_t)((gq*4+m)*JREP)*G3 + c0];
      float s1 = xwA[(size_t)((gq*4+m)*JREP)*G3 + c1];
      #pragma unroll
      for (int k2 = 0; k2 < 6; ++k2){
        int v = ib[k2];
        s0 += GA[((size_t)k2*256 + v)*G3 + c0];
        s1 += GA[((size_t)k2*256 + v)*G3 + c1];
      }
      xwb[m][0][c0] = s0; xwb[m][0][c1] = s1;
    }
  }
  if (doStg) indr[stgM][1][stgK] = in_data[(size_t)(gq*4+stgM)*TT*3 + 6 + stgK];
  __syncthreads();

  for (int t = 0; t < TS; ++t){
    const int nb = t & 1;
    PHASE(0)
    PHASE(1)
    PHASE(2)
    PHASE(3)
    // ---- concurrent epilogues: wave m handles batch m ----
    if (isEpi){
      int i0 = hf*96 + 2*l;
      float2 o0 = *(const float2*)&pg[meW][0][0][i0];  float2 o0b = *(const float2*)&pg[meW][0][1][i0];
      float2 o1 = *(const float2*)&pg[meW][1][0][i0];  float2 o1b = *(const float2*)&pg[meW][1][1][i0];
      float2 o2 = *(const float2*)&pg[meW][2][0][i0];  float2 o2b = *(const float2*)&pg[meW][2][1][i0];
      float2 xr = *(const float2*)&xwb[meW][nb][i0];
      float2 xz = *(const float2*)&xwb[meW][nb][384 + i0];
      float2 xn = *(const float2*)&xwb[meW][nb][768 + i0];
      const unsigned tg = (unsigned)t & 1023u;
      const unsigned* q1 = eq1 + (size_t)nb*G3;
      const unsigned* q2 = eq2 + (size_t)nb*G3;
      const unsigned* q3 = eq3 + (size_t)nb*G3;
      unsigned rv0,rv1,rv2,rv3,rv4,rv5,rv6,rv7,rv8;
      unsigned rv9,rv10,rv11,rv12,rv13,rv14,rv15,rv16,rv17;
      bool ok;
      do {
        ok = true;
        PLW(0,  q1+0) PLW(1,  q1+1) PLW(2,  q1+384) PLW(3,  q1+385) PLW(4,  q1+768) PLW(5,  q1+769)
        PLW(6,  q2+0) PLW(7,  q2+1) PLW(8,  q2+384) PLW(9,  q2+385) PLW(10, q2+768) PLW(11, q2+769)
        PLW(12, q3+0) PLW(13, q3+1) PLW(14, q3+384) PLW(15, q3+385) PLW(16, q3+768) PLW(17, q3+769)
        if (!ok) __builtin_amdgcn_s_sleep(1);
      } while (!ok);
      __builtin_amdgcn_sched_barrier(0);
      #define FVV(n) __builtin_bit_cast(float, rv##n & 0xFFFFFC00u)
      float R0 = o0.x + o0b.x + FVV(0)  + FVV(6)  + FVV(12) + xr.x;
      float R1 = o0.y + o0b.y + FVV(1)  + FVV(7)  + FVV(13) + xr.y;
      float Z0 = o1.x + o1b.x + FVV(2)  + FVV(8)  + FVV(14) + xz.x;
      float Z1 = o1.y + o1b.y + FVV(3)  + FVV(9)  + FVV(15) + xz.y;
      float G0 = o2.x + o2b.x + FVV(4)  + FVV(10) + FVV(16) + bn0;
      float G1 = o2.y + o2b.y + FVV(5)  + FVV(11) + FVV(17) + bn1;
      #undef FVV
      float rr0 = sigmf_(R0), zz0 = sigmf_(Z0);
      float nn0 = tanhf_(xn.x + rr0*G0);
      float h0 = (1.f - zz0)*nn0 + zz0*hreg0; hreg0 = h0;
      float rr1 = sigmf_(R1), zz1 = sigmf_(Z1);
      float nn1 = tanhf_(xn.y + rr1*G1);
      float h1 = (1.f - zz1)*nn1 + zz1*hreg1; hreg1 = h1;
      unsigned pack = pk2_(h0, h1);
      h16u[meW][l] = pack;
      g1u[g1base + (size_t)t*192] = pack;
    }
    bar_lgkm();
  }
}

// ---------------- xW_B = g1 @ gb_wih[:, :384].T + xWrepB (f16 dot2, LDS-staged weights) ----------
__global__ __launch_bounds__(256) void k_xwB(const unsigned* g1u, const float* wih,
                                             const float* xwrB, float* xwB){
  __shared__ __align__(16) unsigned gl[16*194];   // 16 t × 192 h2 pairs (padded)
  __shared__ __align__(16) unsigned wl[48*194];   // 48 rows × 192 h2 pairs (padded)
  int bi = blockIdx.x; int b = bi/55; int t0 = (bi%55)*16; int tid = threadIdx.x;
  for (int idx = tid; idx < 48*192; idx += 256){
    int r = idx/192, cp = idx%192;
    wl[r*194+cp] = pk2_(wih[r*512 + 2*cp], wih[r*512 + 2*cp + 1]);
  }
  for (int idx = tid; idx < 16*192; idx += 256){
    int tt = idx/192, c = idx%192;
    gl[tt*194+c] = g1u[((size_t)b*TS + t0+tt)*192 + c];
  }
  __syncthreads();
  int rr = tid>>4, tt = tid&15;
  int t = t0+tt;
  const float* xr = xwrB + ((size_t)(b*JREP) + t/80)*48;
  const h2v* gp = (const h2v*)&gl[tt*194];
  for (int rb = 0; rb < 3; ++rb){
    int r = rb*16 + rr;
    const h2v* wp_ = (const h2v*)&wl[r*194];
    float acc = 0.f;
    #pragma unroll 8
    for (int c = 0; c < 192; ++c) acc = fdot2_(gp[c], wp_[c], acc);
    xwB[((size_t)b*TS + t)*48 + r] = acc + xr[r];
  }
}

// ---------------- GRU-B scan (tiny, prefetch-pipelined) ----------------
__global__ __launch_bounds__(64) void k_scanB(const float* xwB, const float* whh,
                                              const float* bhh, float* g2){
  __shared__ float wl[48*17];
  __shared__ float h2s[16];
  __shared__ float pre[32];
  __shared__ float xn[16], gn[16];
  int b = blockIdx.x, tid = threadIdx.x;
  for (int idx = tid; idx < 768; idx += 64) wl[(idx>>4)*17 + (idx&15)] = whh[idx];
  if (tid < 16) h2s[tid] = 0.f;
  float bn = (tid >= 32 && tid < 48) ? bhh[tid] : 0.f;
  float xw_n = (tid < 48) ? xwB[(size_t)b*TS*48 + tid] : 0.f;
  __syncthreads();
  for (int t = 0; t < TS; ++t){
    float xw = xw_n;
    if (t+1 < TS && tid < 48) xw_n = xwB[((size_t)b*TS + t+1)*48 + tid];
    if (tid < 48){
      float gh = 0.f;
      #pragma unroll
      for (int e = 0; e < 16; ++e) gh += wl[tid*17+e]*h2s[e];
      if (tid < 32) pre[tid] = xw + gh;
      else { xn[tid-32] = xw; gn[tid-32] = gh + bn; }
    }
    __syncthreads();
    if (tid < 16){
      float r = sigmf_(pre[tid]), z = sigmf_(pre[16+tid]);
      float n = tanhf_(xn[tid] + r*gn[tid]);
      float hn = (1.f - z)*n + z*h2s[tid];
      h2s[tid] = hn;
      g2[((size_t)b*TS + t)*16 + tid] = hn;
    }
    __syncthreads();
  }
}

// ---------------- mdense + output interleave ----------------
__global__ __launch_bounds__(256) void k_out(const float* g2, const int* targets, const float* T2,
    const float* m1w1, const float* m1w2, const float* m1b1, const float* m1b2,
    const float* m1f1, const float* m1f2,
    const float* m2w1, const float* m2w2, const float* m2b1, const float* m2b2,
    const float* m2f1, const float* m2f2, float* out)
{
  __shared__ float wA[256*17], wB[256*17], wC[256*17], wD[256*17];
  __shared__ float g2l[16*16];
  int bi = blockIdx.x; int b = bi/55; int t0 = (bi%55)*16; int c = threadIdx.x;
  for (int d = 0; d < 16; ++d){
    wA[c*17+d] = m1w1[c*16+d];  wB[c*17+d] = m1w2[c*16+d];
    wC[c*17+d] = m2w1[c*144+d]; wD[c*17+d] = m2w2[c*144+d];
  }
  { int tt = c>>4, d = c&15; g2l[c] = g2[((size_t)b*TS + t0+tt)*16 + d]; }
  __syncthreads();
  float b1a = m1b1[c], b2a = m1b2[c], f1a = m1f1[c], f2a = m1f2[c];
  float b1b = m2b1[c], b2b = m2b2[c], f1b = m2f1[c], f2b = m2f2[c];
  for (int tt = 0; tt < 16; ++tt){
    int t = t0+tt;
    float d1 = b1a, d2 = b2a, e1 = b1b, e2 = b2b;
    for (int d = 0; d < 16; ++d){
      float g = g2l[tt*16+d];
      d1 += g*wA[c*17+d]; d2 += g*wB[c*17+d];
      e1 += g*wC[c*17+d]; e2 += g*wD[c*17+d];
    }
    int v = targets[b*TT + 2*t];
    e1 += T2[v*256+c]; e2 += T2[65536 + v*256+c];
    float o1 = f1a*tanhf_(d1) + f2a*tanhf_(d2);
    float o2 = f1b*tanhf_(e1) + f2b*tanhf_(e2);
    size_t base = ((size_t)b*TS + t)*2*256;
    out[base + c]       = o1;
    out[base + 256 + c] = o2;
  }
}

extern "C" void kernel_launch(void* const* d_in, const int* in_sizes, int n_in,
                              void* d_out, int out_size, void* d_ws, size_t ws_size,
                              hipStream_t stream) {
  const int*   in_data = (const int*)  d_in[0];
  const float* feat    = (const float*)d_in[1];
  const int*   periods = (const int*)  d_in[2];
  const int*   targets = (const int*)  d_in[3];
  const float* embp    = (const float*)d_in[4];
  const float* embs    = (const float*)d_in[5];
  const float* c1w = (const float*)d_in[6];  const float* c1b = (const float*)d_in[7];
  const float* c2w = (const float*)d_in[8];  const float* c2b = (const float*)d_in[9];
  const float* f1w = (const float*)d_in[10]; const float* f1b = (const float*)d_in[11];
  const float* f2w = (const float*)d_in[12]; const float* f2b = (const float*)d_in[13];
  const float* ga_wih = (const float*)d_in[14]; const float* ga_whh = (const float*)d_in[15];
  const float* ga_bih = (const float*)d_in[16]; const float* ga_bhh = (const float*)d_in[17];
  const float* gb_wih = (const float*)d_in[18]; const float* gb_whh = (const float*)d_in[19];
  const float* gb_bih = (const float*)d_in[20]; const float* gb_bhh = (const float*)d_in[21];
  const float* m1w1 = (const float*)d_in[22]; const float* m1w2 = (const float*)d_in[23];
  const float* m1b1 = (const float*)d_in[24]; const float* m1b2 = (const float*)d_in[25];
  const float* m1f1 = (const float*)d_in[26]; const float* m1f2 = (const float*)d_in[27];
  const float* m2w1 = (const float*)d_in[28]; const float* m2w2 = (const float*)d_in[29];
  const float* m2b1 = (const float*)d_in[30]; const float* m2b2 = (const float*)d_in[31];
  const float* m2f1 = (const float*)d_in[32]; const float* m2f2 = (const float*)d_in[33];
  float* out = (float*)d_out;

  // workspace layout (floats)
  float* GA     = (float*)d_ws;                  // 6*256*1152     = 1,769,472
  float* xWrepA = GA     + 1769472;              // 704*1152       =   811,008
  float* xWrepB = xWrepA + 811008;               // 704*48         =    33,792
  float* fbuf   = xWrepB + 33792;                // 704*128        =    90,112
  float* xWB    = fbuf   + 90112;                // 56320*48       = 2,703,360
  float* g2buf  = xWB    + 2703360;              // 56320*16       =   901,120
  float* T2     = g2buf  + 901120;               // 2*256*256      =   131,072
  _Float16* Wpk = (_Float16*)(T2 + 131072);      // 442,368 halves
  unsigned* pbuf = (unsigned*)(Wpk + 442368);    // 64*4*2*1152 u32 = 589,824
  _Float16* g1  = (_Float16*)d_out;              // scratch inside output buffer (43.3MB < 115MB)

  (void)hipMemsetAsync(pbuf, 0xFF, 589824*sizeof(unsigned), stream);
  hipLaunchKernelGGL(k_frame, dim3(64), dim3(128), 0, stream,
                     feat, periods, embp, c1w, c1b, c2w, c2b, f1w, f1b, f2w, f2b, fbuf);
  hipLaunchKernelGGL(k_wpack5, dim3(1728), dim3(256), 0, stream, ga_whh, Wpk);
  hipLaunchKernelGGL(k_tables, dim3(108), dim3(256), 0, stream, ga_wih, embs, GA);
  hipLaunchKernelGGL(k_t2, dim3(8), dim3(256), 0, stream, m2w1, m2w2, embs, T2);
  hipLaunchKernelGGL(k_xwrepA, dim3(18), dim3(256), 0, stream, ga_wih, fbuf, ga_bih, ga_bhh, xWrepA);
  hipLaunchKernelGGL(k_xwrepB, dim3(64), dim3(256), 0, stream, gb_wih, fbuf, gb_bih, gb_bhh, xWrepB);
  hipLaunchKernelGGL(k_scanA12, dim3(64), dim3(768), 0, stream,
                     in_data, GA, xWrepA, (const uint4*)Wpk, ga_bhh,
                     (unsigned*)g1, pbuf);
  hipLaunchKernelGGL(k_xwB, dim3(64*55), dim3(256), 0, stream,
                     (const unsigned*)g1, gb_wih, xWrepB, xWB);
  hipLaunchKernelGGL(k_scanB, dim3(64), dim3(64), 0, stream, xWB, gb_whh, gb_bhh, g2buf);
  hipLaunchKernelGGL(k_out, dim3(64*55), dim3(256), 0, stream,
                     g2buf, targets, T2, m1w1, m1w2, m1b1, m1b2, m1f1, m1f2,
                     m2w1, m2w2, m2b1, m2b2, m2f1, m2f2, out);
}

// Round 13
// 3644.609 us; speedup vs baseline: 2.5706x; 2.5706x over previous
//
#include <hip/hip_runtime.h>
#include <hip/hip_bf16.h>
#include <hip/hip_fp16.h>

#define NF    15
#define NBF   20
#define TT    1760
#define TS    880
#define EP    64
#define ES    128
#define DF    128
#define H1    384
#define G3    1152
#define INA   896
#define JREP  11

typedef _Float16 h2v __attribute__((ext_vector_type(2)));
typedef unsigned long long u64;

__device__ __forceinline__ float sigmf_(float x){ return 1.0f/(1.0f + __expf(-x)); }
__device__ __forceinline__ float tanhf_(float x){ return 2.0f/(1.0f + __expf(-2.0f*x)) - 1.0f; }
__device__ __forceinline__ h2v bc_h2(unsigned u){ return __builtin_bit_cast(h2v, u); }
__device__ __forceinline__ float fdot2_(h2v a, h2v b, float c){
#if __has_builtin(__builtin_amdgcn_fdot2)
  return __builtin_amdgcn_fdot2(a, b, c, false);
#else
  return c + (float)a[0]*(float)b[0] + (float)a[1]*(float)b[1];
#endif
}
__device__ __forceinline__ unsigned pk2_(float a, float b){
#if __has_builtin(__builtin_amdgcn_cvt_pkrtz)
  return __builtin_bit_cast(unsigned, __builtin_amdgcn_cvt_pkrtz(a, b));
#else
  unsigned lo = (unsigned)__builtin_bit_cast(unsigned short, (_Float16)a);
  unsigned hi = (unsigned)__builtin_bit_cast(unsigned short, (_Float16)b);
  return lo | (hi << 16);
#endif
}
__device__ __forceinline__ void bar_lgkm(){
  asm volatile("s_waitcnt lgkmcnt(0)" ::: "memory");
  __builtin_amdgcn_s_barrier();
  __builtin_amdgcn_sched_barrier(0);
}

// ---------------- frame-rate network: f[64][11][128] ----------------
__global__ __launch_bounds__(128) void k_frame(const float* feat, const int* periods, const float* embp,
   const float* c1w, const float* c1b, const float* c2w, const float* c2b,
   const float* f1w, const float* f1b, const float* f2w, const float* f2b, float* fout)
{
  __shared__ float cat[NF*84];
  __shared__ float x1[13*DF];
  __shared__ float x2[JREP*DF];
  int b = blockIdx.x, tid = threadIdx.x;
  for (int idx = tid; idx < NF*84; idx += 128){
    int j = idx/84, c = idx%84;
    cat[idx] = (c < NBF) ? feat[(b*NF+j)*NBF + c]
                         : embp[periods[b*NF+j]*EP + (c-NBF)];
  }
  __syncthreads();
  int o = tid;
  for (int p = 0; p < 13; ++p){
    float acc = c1b[o];
    for (int kk = 0; kk < 3; ++kk)
      for (int c = 0; c < 84; ++c)
        acc += cat[(p+kk)*84 + c] * c1w[(o*84+c)*3+kk];
    x1[p*DF+o] = tanhf_(acc);
  }
  __syncthreads();
  for (int p = 0; p < JREP; ++p){
    float acc = c2b[o];
    for (int kk = 0; kk < 3; ++kk)
      for (int c = 0; c < DF; ++c)
        acc += x1[(p+kk)*DF+c] * c2w[(o*DF+c)*3+kk];
    x2[p*DF+o] = tanhf_(acc);
  }
  __syncthreads();
  for (int p = 0; p < JREP; ++p){
    float acc = f1b[o];
    for (int c = 0; c < DF; ++c) acc += x2[p*DF+c]*f1w[o*DF+c];
    x1[p*DF+o] = tanhf_(acc);
  }
  __syncthreads();
  for (int p = 0; p < JREP; ++p){
    float acc = f2b[o];
    for (int c = 0; c < DF; ++c) acc += x1[p*DF+c]*f2w[o*DF+c];
    fout[(b*JREP+p)*DF+o] = tanhf_(acc);
  }
}

// ---------------- pack ga_whh f32 -> per-(hf,thread) uint4-contiguous f16 (j-quarter split) ------
__global__ __launch_bounds__(256) void k_wpack5(const float* whh, _Float16* wpk){
  int o = blockIdx.x*256 + threadIdx.x;        // < 442368
  int hu = o & 1;
  int c  = (o >> 1) & 3;
  int idx = o >> 3;                            // uint4 index
  int tid = idx % 768;
  int n   = (idx / 768) % 18;
  int hf  = idx / (768*18);
  int i = tid % 384, u = tid / 384;
  int gd = n*4 + c;
  int m = gd / 12, dc = gd % 12;
  int pos  = (dc % 2) + 2*(dc / 6);
  int gate = (dc % 6) >> 1;
  int j = hf*96 + u*48 + (4*m + pos)*2 + hu;
  wpk[o] = (_Float16)whh[(gate*H1 + i)*H1 + j];
}

// ---------------- GA tables: GA[k][256][1152] ----------------
__global__ __launch_bounds__(256) void k_tables(const float* wih, const float* emb, float* GA){
  __shared__ float Wl[64*129];
  int k = blockIdx.x/18, g0 = (blockIdx.x%18)*64;
  int tid = threadIdx.x;
  for (int idx = tid; idx < 64*128; idx += 256){
    int gg = idx>>7, c = idx&127;
    Wl[gg*129+c] = wih[(size_t)(g0+gg)*INA + k*128 + c];
  }
  __syncthreads();
  int vv = tid>>6, gg = tid&63;
  for (int v = vv; v < 256; v += 4){
    const float* e = emb + (size_t)v*ES;
    float acc = 0.f;
    for (int c = 0; c < 128; ++c) acc += e[c]*Wl[gg*129+c];
    GA[(size_t)(k*256+v)*G3 + g0+gg] = acc;
  }
}

// ---------------- xWrepA[b][j][1152] ----------------
__global__ __launch_bounds__(256) void k_xwrepA(const float* wih, const float* f,
                                                const float* bih, const float* bhh, float* xwA){
  __shared__ float Wl[64*129];
  int g0 = blockIdx.x*64, tid = threadIdx.x;
  for (int idx = tid; idx < 64*128; idx += 256){
    int gg = idx>>7, c = idx&127;
    Wl[gg*129+c] = wih[(size_t)(g0+gg)*INA + 768 + c];
  }
  __syncthreads();
  int vv = tid>>6, gg = tid&63; int g = g0+gg;
  float badd = bih[g] + (g < 768 ? bhh[g] : 0.f);
  for (int row = vv; row < 64*JREP; row += 4){
    const float* fr = f + (size_t)row*DF;
    float acc = badd;
    for (int c = 0; c < 128; ++c) acc += fr[c]*Wl[gg*129+c];
    xwA[(size_t)row*G3 + g] = acc;
  }
}

// ---------------- xWrepB[b][j][48] ----------------
__global__ __launch_bounds__(256) void k_xwrepB(const float* wih, const float* f,
                                                const float* bih, const float* bhh, float* xwB){
  __shared__ float Wl[48*129];
  int b = blockIdx.x, tid = threadIdx.x;
  for (int idx = tid; idx < 48*128; idx += 256){
    int r = idx>>7, c = idx&127;
    Wl[r*129+c] = wih[r*512 + 384 + c];
  }
  __syncthreads();
  for (int idx = tid; idx < JREP*48; idx += 256){
    int j = idx/48, r = idx%48;
    const float* fr = f + (size_t)(b*JREP+j)*DF;
    float acc = bih[r] + (r < 32 ? bhh[r] : 0.f);
    for (int c = 0; c < 128; ++c) acc += fr[c]*Wl[r*129+c];
    xwB[(size_t)(b*JREP+j)*48 + r] = acc;
  }
}

// ---------------- md2 embed tables: T2[tbl][256][256] ----------------
__global__ __launch_bounds__(256) void k_t2(const float* w1, const float* w2, const float* emb, float* T2){
  __shared__ float Wl[64*129];
  int tbl = blockIdx.x>>2; int c0 = (blockIdx.x&3)*64; int tid = threadIdx.x;
  const float* w = tbl ? w2 : w1;
  for (int idx = tid; idx < 64*128; idx += 256){
    int cc = idx>>7, e = idx&127;
    Wl[cc*129+e] = w[(c0+cc)*144 + 16 + e];
  }
  __syncthreads();
  int vv = tid>>6, cc = tid&63;
  for (int v = vv; v < 256; v += 4){
    const float* e = emb + (size_t)v*ES;
    float acc = 0.f;
    for (int c = 0; c < 128; ++c) acc += e[c]*Wl[cc*129+c];
    T2[tbl*65536 + v*256 + c0+cc] = acc;
  }
}

// ---------------- GRU-A scan v13: R9 structure, vectorized consumer polls ----------------
#define LD18(n) uint4 d##n = wsrc[(size_t)(n)*768];
#define Q2(A,B,C, q2) { \
  h2v hA = hh[jb2 + (q2)*2],     hB = hh[jb2 + (q2)*2 + 1]; \
  ar = fdot2_(hA, bc_h2(A.x), ar); ar = fdot2_(hB, bc_h2(A.y), ar); \
  az = fdot2_(hA, bc_h2(A.z), az); az = fdot2_(hB, bc_h2(A.w), az); \
  an = fdot2_(hA, bc_h2(B.x), an); an = fdot2_(hB, bc_h2(B.y), an); \
  h2v hC = hh[jb2 + (q2)*2 + 2], hD = hh[jb2 + (q2)*2 + 3]; \
  ar = fdot2_(hC, bc_h2(B.z), ar); ar = fdot2_(hD, bc_h2(B.w), ar); \
  az = fdot2_(hC, bc_h2(C.x), az); az = fdot2_(hD, bc_h2(C.y), az); \
  an = fdot2_(hC, bc_h2(C.z), an); an = fdot2_(hD, bc_h2(C.w), an); }
#define DOTS12 \
  Q2(d0,d1,d2,0) Q2(d3,d4,d5,2) Q2(d6,d7,d8,4) \
  Q2(d9,d10,d11,6) Q2(d12,d13,d14,8) Q2(d15,d16,d17,10)

#define PL2(na, nb_, p) { u64 w2 = __hip_atomic_load((const u64*)(p), __ATOMIC_RELAXED, __HIP_MEMORY_SCOPE_AGENT); \
  rv##na = (unsigned)w2; rv##nb_ = (unsigned)(w2 >> 32); \
  ok &= ((rv##na & 1023u) == tg) & ((rv##nb_ & 1023u) == tg); }

__global__ __launch_bounds__(768, 3) void k_scanA13(const int* __restrict__ in_data,
        const float* __restrict__ GA, const float* __restrict__ xwA,
        const uint4* __restrict__ wpk, const float* __restrict__ bhh,
        unsigned* __restrict__ g1u, unsigned* pbuf)
{
  __shared__ __align__(16) unsigned h16u[48];     // own j-quarter h(t-1): 96 rows = 48 u32
  __shared__ __align__(8)  float pg[3][2][384];   // own-quarter partials [gate][u][out-row]
  __shared__ __align__(8)  float xwb[2][G3];      // xW double buffer
  __shared__ int indr[2][8];
  const int P = blockIdx.x;
  const int b = P & 63, hf = P >> 6;
  const int tid = threadIdx.x;
  const int i  = tid % 384;                       // output row (global)
  const int u  = tid / 384;                       // j-half of own quarter
  const int jb2 = u * 24;                         // h2 base into h16u
  const int* ind_b = in_data + (size_t)b*TT*3;

  // weights: 18 uint4 (j-quarter slice), loaded once
  const uint4* wsrc = wpk + (size_t)(hf*18)*768 + tid;
  LD18(0) LD18(1) LD18(2) LD18(3) LD18(4) LD18(5) LD18(6) LD18(7) LD18(8)
  LD18(9) LD18(10) LD18(11) LD18(12) LD18(13) LD18(14) LD18(15) LD18(16) LD18(17)

  const bool isGat = (tid < 576);
  const int  c0 = 2*tid, c1 = 2*tid + 1;          // gather col pair (isGat)
  const bool isPub = (tid >= 96 && tid < 672);
  const int  po0 = 2*(tid - 96);                  // publish output pair (isPub)

  float hreg0 = 0.f, hreg1 = 0.f, bn0 = 0.f, bn1 = 0.f;
  if (tid < 48){
    bn0 = bhh[768 + hf*96 + 2*tid];
    bn1 = bhh[768 + hf*96 + 2*tid + 1];
    h16u[tid] = 0u;
  }
  // prologue: xwb[0] for t=0 ; indices for t=1
  if (isGat){
    float s0 = xwA[(size_t)(b*JREP)*G3 + c0];
    float s1 = xwA[(size_t)(b*JREP)*G3 + c1];
    #pragma unroll
    for (int k2 = 0; k2 < 6; ++k2){
      int v = ind_b[k2];
      s0 += GA[((size_t)k2*256 + v)*G3 + c0];
      s1 += GA[((size_t)k2*256 + v)*G3 + c1];
    }
    xwb[0][c0] = s0; xwb[0][c1] = s1;
  }
  if (tid >= 576 && tid < 582) indr[1][tid-576] = ind_b[6 + (tid-576)];

  unsigned* pbo = pbuf + ((size_t)(b*4 + hf)*2)*G3;                 // own publish base
  const int pf1 = (hf+1)&3, pf2 = (hf+2)&3, pf3 = (hf+3)&3;
  const unsigned* pb1 = pbuf + ((size_t)(b*4 + pf1)*2)*G3 + hf*96 + 2*(tid<48?tid:0);
  const unsigned* pb2 = pbuf + ((size_t)(b*4 + pf2)*2)*G3 + hf*96 + 2*(tid<48?tid:0);
  const unsigned* pb3 = pbuf + ((size_t)(b*4 + pf3)*2)*G3 + hf*96 + 2*(tid<48?tid:0);
  const h2v* hh = (const h2v*)h16u;
  __syncthreads();

  for (int t = 0; t < TS; ++t){
    const int nb = t & 1;
    // ---- phase 1: issue xW gathers for t+1, dots on OWN h-quarter (no remote wait) ----
    const int tp = t + 1;
    float ga0=0.f,ga1=0.f,ga2=0.f,ga3=0.f,ga4=0.f,ga5=0.f,gx0=0.f;
    float gb0=0.f,gb1=0.f,gb2=0.f,gb3=0.f,gb4=0.f,gb5=0.f,gx1=0.f;
    if (tp < TS && isGat){
      int v0=indr[tp&1][0], v1=indr[tp&1][1], v2=indr[tp&1][2];
      int v3=indr[tp&1][3], v4=indr[tp&1][4], v5=indr[tp&1][5];
      const float* xwr = xwA + ((size_t)(b*JREP) + tp/80)*G3;
      ga0 = GA[((size_t)0*256 + v0)*G3 + c0]; gb0 = GA[((size_t)0*256 + v0)*G3 + c1];
      ga1 = GA[((size_t)1*256 + v1)*G3 + c0]; gb1 = GA[((size_t)1*256 + v1)*G3 + c1];
      ga2 = GA[((size_t)2*256 + v2)*G3 + c0]; gb2 = GA[((size_t)2*256 + v2)*G3 + c1];
      ga3 = GA[((size_t)3*256 + v3)*G3 + c0]; gb3 = GA[((size_t)3*256 + v3)*G3 + c1];
      ga4 = GA[((size_t)4*256 + v4)*G3 + c0]; gb4 = GA[((size_t)4*256 + v4)*G3 + c1];
      ga5 = GA[((size_t)5*256 + v5)*G3 + c0]; gb5 = GA[((size_t)5*256 + v5)*G3 + c1];
      gx0 = xwr[c0]; gx1 = xwr[c1];
    }
    int iv = 0;
    const int stg = t + 2;
    const bool doStg = (tid >= 576 && tid < 582 && stg < TS);
    if (doStg) iv = ind_b[6*stg + (tid-576)];
    // dots: 72 fdot2 against resident weights; h from own-quarter LDS (broadcast reads)
    float ar=0.f, az=0.f, an=0.f;
    DOTS12
    pg[0][u][i] = ar; pg[1][u][i] = az; pg[2][u][i] = an;
    if (tp < TS && isGat){
      xwb[tp&1][c0] = ga0+ga1+ga2+ga3+ga4+ga5+gx0;
      xwb[tp&1][c1] = gb0+gb1+gb2+gb3+gb4+gb5+gx1;
    }
    if (doStg) indr[t&1][tid-576] = iv;
    bar_lgkm();
    // ---- phase 2: publishers push tagged partials; epilogue lanes poll + update h ----
    if (isPub){
      int g = po0/384, ii = po0 - g*384;
      float2 p0 = *(const float2*)&pg[g][0][ii];
      float2 p1 = *(const float2*)&pg[g][1][ii];
      float v0 = p0.x + p1.x, v1 = p0.y + p1.y;
      unsigned tw0 = (__builtin_bit_cast(unsigned, v0) & 0xFFFFFC00u) | (unsigned)(t & 1023);
      unsigned tw1 = (__builtin_bit_cast(unsigned, v1) & 0xFFFFFC00u) | (unsigned)(t & 1023);
      unsigned* dst = pbo + (size_t)nb*G3 + po0;
      __hip_atomic_store(dst,     tw0, __ATOMIC_RELAXED, __HIP_MEMORY_SCOPE_AGENT);
      __hip_atomic_store(dst + 1, tw1, __ATOMIC_RELAXED, __HIP_MEMORY_SCOPE_AGENT);
    } else if (tid < 48){
      const unsigned tg = (unsigned)t & 1023u;
      const unsigned* q1 = pb1 + (size_t)nb*G3;
      const unsigned* q2 = pb2 + (size_t)nb*G3;
      const unsigned* q3 = pb3 + (size_t)nb*G3;
      unsigned rv0,rv1,rv2,rv3,rv4,rv5,rv6,rv7,rv8;
      unsigned rv9,rv10,rv11,rv12,rv13,rv14,rv15,rv16,rv17;
      bool ok;
      do {
        ok = true;
        PL2(0,1,   q1+0) PL2(2,3,   q1+384) PL2(4,5,   q1+768)
        PL2(6,7,   q2+0) PL2(8,9,   q2+384) PL2(10,11, q2+768)
        PL2(12,13, q3+0) PL2(14,15, q3+384) PL2(16,17, q3+768)
        if (!ok) __builtin_amdgcn_s_sleep(1);
      } while (!ok);
      __builtin_amdgcn_sched_barrier(0);
      #define FV(n) __builtin_bit_cast(float, rv##n & 0xFFFFFC00u)
      int i0 = hf*96 + 2*tid;
      float2 o0 = *(const float2*)&pg[0][0][i0];  float2 o0b = *(const float2*)&pg[0][1][i0];
      float2 o1 = *(const float2*)&pg[1][0][i0];  float2 o1b = *(const float2*)&pg[1][1][i0];
      float2 o2 = *(const float2*)&pg[2][0][i0];  float2 o2b = *(const float2*)&pg[2][1][i0];
      float2 xr = *(const float2*)&xwb[nb][i0];
      float2 xz = *(const float2*)&xwb[nb][384 + i0];
      float2 xn = *(const float2*)&xwb[nb][768 + i0];
      float R0 = o0.x + o0b.x + FV(0)  + FV(6)  + FV(12) + xr.x;
      float R1 = o0.y + o0b.y + FV(1)  + FV(7)  + FV(13) + xr.y;
      float Z0 = o1.x + o1b.x + FV(2)  + FV(8)  + FV(14) + xz.x;
      float Z1 = o1.y + o1b.y + FV(3)  + FV(9)  + FV(15) + xz.y;
      float G0 = o2.x + o2b.x + FV(4)  + FV(10) + FV(16) + bn0;
      float G1 = o2.y + o2b.y + FV(5)  + FV(11) + FV(17) + bn1;
      #undef FV
      float rr0 = sigmf_(R0), zz0 = sigmf_(Z0);
      float nn0 = tanhf_(xn.x + rr0*G0);
      float h0 = (1.f - zz0)*nn0 + zz0*hreg0; hreg0 = h0;
      float rr1 = sigmf_(R1), zz1 = sigmf_(Z1);
      float nn1 = tanhf_(xn.y + rr1*G1);
      float h1 = (1.f - zz1)*nn1 + zz1*hreg1; hreg1 = h1;
      unsigned pack = pk2_(h0, h1);
      h16u[tid] = pack;
      g1u[((size_t)b*TS + t)*192 + hf*48 + tid] = pack;
    }
    bar_lgkm();
  }
}

// ---------------- xW_B = g1 @ gb_wih[:, :384].T + xWrepB (f16 dot2, LDS-staged weights) ----------
__global__ __launch_bounds__(256) void k_xwB(const unsigned* g1u, const float* wih,
                                             const float* xwrB, float* xwB){
  __shared__ __align__(16) unsigned gl[16*194];   // 16 t × 192 h2 pairs (padded)
  __shared__ __align__(16) unsigned wl[48*194];   // 48 rows × 192 h2 pairs (padded)
  int bi = blockIdx.x; int b = bi/55; int t0 = (bi%55)*16; int tid = threadIdx.x;
  for (int idx = tid; idx < 48*192; idx += 256){
    int r = idx/192, cp = idx%192;
    wl[r*194+cp] = pk2_(wih[r*512 + 2*cp], wih[r*512 + 2*cp + 1]);
  }
  for (int idx = tid; idx < 16*192; idx += 256){
    int tt = idx/192, c = idx%192;
    gl[tt*194+c] = g1u[((size_t)b*TS + t0+tt)*192 + c];
  }
  __syncthreads();
  int rr = tid>>4, tt = tid&15;
  int t = t0+tt;
  const float* xr = xwrB + ((size_t)(b*JREP) + t/80)*48;
  const h2v* gp = (const h2v*)&gl[tt*194];
  for (int rb = 0; rb < 3; ++rb){
    int r = rb*16 + rr;
    const h2v* wp_ = (const h2v*)&wl[r*194];
    float acc = 0.f;
    #pragma unroll 8
    for (int c = 0; c < 192; ++c) acc = fdot2_(gp[c], wp_[c], acc);
    xwB[((size_t)b*TS + t)*48 + r] = acc + xr[r];
  }
}

// ---------------- GRU-B scan: single-wave, shuffle-based (no LDS, no barriers) ----------------
__global__ __launch_bounds__(64) void k_scanB(const float* xwB, const float* whh,
                                              const float* bhh, float* g2){
  int b = blockIdx.x, tid = threadIdx.x;
  float w0=0,w1=0,w2=0,w3=0,w4=0,w5=0,w6=0,w7=0;
  float w8=0,w9=0,w10=0,w11=0,w12=0,w13=0,w14=0,w15=0;
  if (tid < 48){
    const float* wr = whh + tid*16;
    w0=wr[0];w1=wr[1];w2=wr[2];w3=wr[3];w4=wr[4];w5=wr[5];w6=wr[6];w7=wr[7];
    w8=wr[8];w9=wr[9];w10=wr[10];w11=wr[11];w12=wr[12];w13=wr[13];w14=wr[14];w15=wr[15];
  }
  float bng = (tid < 16) ? bhh[32 + tid] : 0.f;
  float hv = 0.f;                               // lanes 0..15 hold h
  float xw_n = (tid < 48) ? xwB[(size_t)b*TS*48 + tid] : 0.f;
  for (int t = 0; t < TS; ++t){
    float xw = xw_n;
    if (t+1 < TS && tid < 48) xw_n = xwB[((size_t)b*TS + t+1)*48 + tid];
    float gh = 0.f;
    gh += w0 *__shfl(hv, 0, 64);  gh += w1 *__shfl(hv, 1, 64);
    gh += w2 *__shfl(hv, 2, 64);  gh += w3 *__shfl(hv, 3, 64);
    gh += w4 *__shfl(hv, 4, 64);  gh += w5 *__shfl(hv, 5, 64);
    gh += w6 *__shfl(hv, 6, 64);  gh += w7 *__shfl(hv, 7, 64);
    gh += w8 *__shfl(hv, 8, 64);  gh += w9 *__shfl(hv, 9, 64);
    gh += w10*__shfl(hv,10, 64);  gh += w11*__shfl(hv,11, 64);
    gh += w12*__shfl(hv,12, 64);  gh += w13*__shfl(hv,13, 64);
    gh += w14*__shfl(hv,14, 64);  gh += w15*__shfl(hv,15, 64);
    float val = xw + gh;                        // lanes 0..31: gate pre-activation
    float zv  = __shfl(val, (tid+16) & 63, 64); // lane r: pre[16+r]
    float xn_ = __shfl(xw,  (tid+32) & 63, 64);
    float gn_ = __shfl(gh,  (tid+32) & 63, 64) + bng;
    if (tid < 16){
      float r = sigmf_(val), z = sigmf_(zv);
      float n = tanhf_(xn_ + r*gn_);
      hv = (1.f - z)*n + z*hv;
      g2[((size_t)b*TS + t)*16 + tid] = hv;
    }
  }
}

// ---------------- mdense + output interleave ----------------
__global__ __launch_bounds__(256) void k_out(const float* g2, const int* targets, const float* T2,
    const float* m1w1, const float* m1w2, const float* m1b1, const float* m1b2,
    const float* m1f1, const float* m1f2,
    const float* m2w1, const float* m2w2, const float* m2b1, const float* m2b2,
    const float* m2f1, const float* m2f2, float* out)
{
  __shared__ float wA[256*17], wB[256*17], wC[256*17], wD[256*17];
  __shared__ float g2l[16*16];
  int bi = blockIdx.x; int b = bi/55; int t0 = (bi%55)*16; int c = threadIdx.x;
  for (int d = 0; d < 16; ++d){
    wA[c*17+d] = m1w1[c*16+d];  wB[c*17+d] = m1w2[c*16+d];
    wC[c*17+d] = m2w1[c*144+d]; wD[c*17+d] = m2w2[c*144+d];
  }
  { int tt = c>>4, d = c&15; g2l[c] = g2[((size_t)b*TS + t0+tt)*16 + d]; }
  __syncthreads();
  float b1a = m1b1[c], b2a = m1b2[c], f1a = m1f1[c], f2a = m1f2[c];
  float b1b = m2b1[c], b2b = m2b2[c], f1b = m2f1[c], f2b = m2f2[c];
  for (int tt = 0; tt < 16; ++tt){
    int t = t0+tt;
    float d1 = b1a, d2 = b2a, e1 = b1b, e2 = b2b;
    for (int d = 0; d < 16; ++d){
      float g = g2l[tt*16+d];
      d1 += g*wA[c*17+d]; d2 += g*wB[c*17+d];
      e1 += g*wC[c*17+d]; e2 += g*wD[c*17+d];
    }
    int v = targets[b*TT + 2*t];
    e1 += T2[v*256+c]; e2 += T2[65536 + v*256+c];
    float o1 = f1a*tanhf_(d1) + f2a*tanhf_(d2);
    float o2 = f1b*tanhf_(e1) + f2b*tanhf_(e2);
    size_t base = ((size_t)b*TS + t)*2*256;
    out[base + c]       = o1;
    out[base + 256 + c] = o2;
  }
}

extern "C" void kernel_launch(void* const* d_in, const int* in_sizes, int n_in,
                              void* d_out, int out_size, void* d_ws, size_t ws_size,
                              hipStream_t stream) {
  const int*   in_data = (const int*)  d_in[0];
  const float* feat    = (const float*)d_in[1];
  const int*   periods = (const int*)  d_in[2];
  const int*   targets = (const int*)  d_in[3];
  const float* embp    = (const float*)d_in[4];
  const float* embs    = (const float*)d_in[5];
  const float* c1w = (const float*)d_in[6];  const float* c1b = (const float*)d_in[7];
  const float* c2w = (const float*)d_in[8];  const float* c2b = (const float*)d_in[9];
  const float* f1w = (const float*)d_in[10]; const float* f1b = (const float*)d_in[11];
  const float* f2w = (const float*)d_in[12]; const float* f2b = (const float*)d_in[13];
  const float* ga_wih = (const float*)d_in[14]; const float* ga_whh = (const float*)d_in[15];
  const float* ga_bih = (const float*)d_in[16]; const float* ga_bhh = (const float*)d_in[17];
  const float* gb_wih = (const float*)d_in[18]; const float* gb_whh = (const float*)d_in[19];
  const float* gb_bih = (const float*)d_in[20]; const float* gb_bhh = (const float*)d_in[21];
  const float* m1w1 = (const float*)d_in[22]; const float* m1w2 = (const float*)d_in[23];
  const float* m1b1 = (const float*)d_in[24]; const float* m1b2 = (const float*)d_in[25];
  const float* m1f1 = (const float*)d_in[26]; const float* m1f2 = (const float*)d_in[27];
  const float* m2w1 = (const float*)d_in[28]; const float* m2w2 = (const float*)d_in[29];
  const float* m2b1 = (const float*)d_in[30]; const float* m2b2 = (const float*)d_in[31];
  const float* m2f1 = (const float*)d_in[32]; const float* m2f2 = (const float*)d_in[33];
  float* out = (float*)d_out;

  // workspace layout (floats)
  float* GA     = (float*)d_ws;                  // 6*256*1152     = 1,769,472
  float* xWrepA = GA     + 1769472;              // 704*1152       =   811,008
  float* xWrepB = xWrepA + 811008;               // 704*48         =    33,792
  float* fbuf   = xWrepB + 33792;                // 704*128        =    90,112
  float* xWB    = fbuf   + 90112;                // 56320*48       = 2,703,360
  float* g2buf  = xWB    + 2703360;              // 56320*16       =   901,120
  float* T2     = g2buf  + 901120;               // 2*256*256      =   131,072
  _Float16* Wpk = (_Float16*)(T2 + 131072);      // 442,368 halves
  unsigned* pbuf = (unsigned*)(Wpk + 442368);    // 64*4*2*1152 u32 = 589,824
  _Float16* g1  = (_Float16*)d_out;              // scratch inside output buffer (43.3MB < 115MB)

  // invalidate partial-tags each launch (stale tag 1023 never matches any t<880)
  (void)hipMemsetAsync(pbuf, 0xFF, 589824*sizeof(unsigned), stream);
  hipLaunchKernelGGL(k_frame, dim3(64), dim3(128), 0, stream,
                     feat, periods, embp, c1w, c1b, c2w, c2b, f1w, f1b, f2w, f2b, fbuf);
  hipLaunchKernelGGL(k_wpack5, dim3(1728), dim3(256), 0, stream, ga_whh, Wpk);
  hipLaunchKernelGGL(k_tables, dim3(108), dim3(256), 0, stream, ga_wih, embs, GA);
  hipLaunchKernelGGL(k_t2, dim3(8), dim3(256), 0, stream, m2w1, m2w2, embs, T2);
  hipLaunchKernelGGL(k_xwrepA, dim3(18), dim3(256), 0, stream, ga_wih, fbuf, ga_bih, ga_bhh, xWrepA);
  hipLaunchKernelGGL(k_xwrepB, dim3(64), dim3(256), 0, stream, gb_wih, fbuf, gb_bih, gb_bhh, xWrepB);
  hipLaunchKernelGGL(k_scanA13, dim3(256), dim3(768), 0, stream,
                     in_data, GA, xWrepA, (const uint4*)Wpk, ga_bhh,
                     (unsigned*)g1, pbuf);
  hipLaunchKernelGGL(k_xwB, dim3(64*55), dim3(256), 0, stream,
                     (const unsigned*)g1, gb_wih, xWrepB, xWB);
  hipLaunchKernelGGL(k_scanB, dim3(64), dim3(64), 0, stream, xWB, gb_whh, gb_bhh, g2buf);
  hipLaunchKernelGGL(k_out, dim3(64*55), dim3(256), 0, stream,
                     g2buf, targets, T2, m1w1, m1w2, m1b1, m1b2, m1f1, m1f2,
                     m2w1, m2w2, m2b1, m2b2, m2f1, m2f2, out);
}

// Round 14
// 3629.297 us; speedup vs baseline: 2.5814x; 1.0042x over previous
//
#include <hip/hip_runtime.h>
#include <hip/hip_bf16.h>
#include <hip/hip_fp16.h>

#define NF    15
#define NBF   20
#define TT    1760
#define TS    880
#define EP    64
#define ES    128
#define DF    128
#define H1    384
#define G3    1152
#define INA   896
#define JREP  11

typedef _Float16 h2v __attribute__((ext_vector_type(2)));
typedef unsigned long long u64;

__device__ __forceinline__ float sigmf_(float x){ return 1.0f/(1.0f + __expf(-x)); }
__device__ __forceinline__ float tanhf_(float x){ return 2.0f/(1.0f + __expf(-2.0f*x)) - 1.0f; }
__device__ __forceinline__ h2v bc_h2(unsigned u){ return __builtin_bit_cast(h2v, u); }
__device__ __forceinline__ float fdot2_(h2v a, h2v b, float c){
#if __has_builtin(__builtin_amdgcn_fdot2)
  return __builtin_amdgcn_fdot2(a, b, c, false);
#else
  return c + (float)a[0]*(float)b[0] + (float)a[1]*(float)b[1];
#endif
}
__device__ __forceinline__ unsigned pk2_(float a, float b){
#if __has_builtin(__builtin_amdgcn_cvt_pkrtz)
  return __builtin_bit_cast(unsigned, __builtin_amdgcn_cvt_pkrtz(a, b));
#else
  unsigned lo = (unsigned)__builtin_bit_cast(unsigned short, (_Float16)a);
  unsigned hi = (unsigned)__builtin_bit_cast(unsigned short, (_Float16)b);
  return lo | (hi << 16);
#endif
}
__device__ __forceinline__ void bar_lgkm(){
  asm volatile("s_waitcnt lgkmcnt(0)" ::: "memory");
  __builtin_amdgcn_s_barrier();
  __builtin_amdgcn_sched_barrier(0);
}

// ============ fused setup A: frame(0..63) | wpack5(64..1791) | tables(1792..1899) | t2(1900..1907)
__global__ __launch_bounds__(256) void k_setupA(const float* feat, const int* periods, const float* embp,
   const float* c1w, const float* c1b, const float* c2w, const float* c2b,
   const float* f1w, const float* f1b, const float* f2w, const float* f2b, float* fout,
   const float* whh, _Float16* wpk,
   const float* wih, const float* emb, float* GA,
   const float* m2w1, const float* m2w2, float* T2)
{
  __shared__ float sh[8256];
  const int bi = blockIdx.x, tid = threadIdx.x;
  if (bi < 64){
    // ---- frame-rate network ----
    float* cat = sh;            // 15*84 = 1260
    float* x1  = sh + 1260;     // 13*128 = 1664
    float* x2  = sh + 2924;     // 11*128 = 1408
    int b = bi;
    for (int idx = tid; idx < NF*84; idx += 256){
      int j = idx/84, c = idx%84;
      cat[idx] = (c < NBF) ? feat[(b*NF+j)*NBF + c]
                           : embp[periods[b*NF+j]*EP + (c-NBF)];
    }
    __syncthreads();
    int o = tid;
    if (o < DF){
      for (int p = 0; p < 13; ++p){
        float acc = c1b[o];
        for (int kk = 0; kk < 3; ++kk)
          for (int c = 0; c < 84; ++c)
            acc += cat[(p+kk)*84 + c] * c1w[(o*84+c)*3+kk];
        x1[p*DF+o] = tanhf_(acc);
      }
    }
    __syncthreads();
    if (o < DF){
      for (int p = 0; p < JREP; ++p){
        float acc = c2b[o];
        for (int kk = 0; kk < 3; ++kk)
          for (int c = 0; c < DF; ++c)
            acc += x1[(p+kk)*DF+c] * c2w[(o*DF+c)*3+kk];
        x2[p*DF+o] = tanhf_(acc);
      }
    }
    __syncthreads();
    if (o < DF){
      for (int p = 0; p < JREP; ++p){
        float acc = f1b[o];
        for (int c = 0; c < DF; ++c) acc += x2[p*DF+c]*f1w[o*DF+c];
        x1[p*DF+o] = tanhf_(acc);
      }
    }
    __syncthreads();
    if (o < DF){
      for (int p = 0; p < JREP; ++p){
        float acc = f2b[o];
        for (int c = 0; c < DF; ++c) acc += x1[p*DF+c]*f2w[o*DF+c];
        fout[(b*JREP+p)*DF+o] = tanhf_(acc);
      }
    }
  } else if (bi < 1792){
    // ---- wpack5: ga_whh -> per-(hf,thread) uint4-contiguous f16 (j-quarter split) ----
    int o = (bi-64)*256 + tid;                   // < 442368
    int hu = o & 1;
    int c  = (o >> 1) & 3;
    int idx = o >> 3;
    int t768 = idx % 768;
    int n    = (idx / 768) % 18;
    int hf   = idx / (768*18);
    int i = t768 % 384, u = t768 / 384;
    int gd = n*4 + c;
    int m = gd / 12, dc = gd % 12;
    int pos  = (dc % 2) + 2*(dc / 6);
    int gate = (dc % 6) >> 1;
    int j = hf*96 + u*48 + (4*m + pos)*2 + hu;
    wpk[o] = (_Float16)whh[(gate*H1 + i)*H1 + j];
  } else if (bi < 1900){
    // ---- GA tables ----
    float* Wl = sh;
    int bb = bi - 1792;
    int k = bb/18, g0 = (bb%18)*64;
    for (int idx = tid; idx < 64*128; idx += 256){
      int gg = idx>>7, c = idx&127;
      Wl[gg*129+c] = wih[(size_t)(g0+gg)*INA + k*128 + c];
    }
    __syncthreads();
    int vv = tid>>6, gg = tid&63;
    for (int v = vv; v < 256; v += 4){
      const float* e = emb + (size_t)v*ES;
      float acc = 0.f;
      for (int c = 0; c < 128; ++c) acc += e[c]*Wl[gg*129+c];
      GA[(size_t)(k*256+v)*G3 + g0+gg] = acc;
    }
  } else {
    // ---- T2 tables ----
    float* Wl = sh;
    int bb = bi - 1900;
    int tbl = bb>>2; int c0 = (bb&3)*64;
    const float* w = tbl ? m2w2 : m2w1;
    for (int idx = tid; idx < 64*128; idx += 256){
      int cc = idx>>7, e = idx&127;
      Wl[cc*129+e] = w[(c0+cc)*144 + 16 + e];
    }
    __syncthreads();
    int vv = tid>>6, cc = tid&63;
    for (int v = vv; v < 256; v += 4){
      const float* e = emb + (size_t)v*ES;
      float acc = 0.f;
      for (int c = 0; c < 128; ++c) acc += e[c]*Wl[cc*129+c];
      T2[tbl*65536 + v*256 + c0+cc] = acc;
    }
  }
}

// ============ fused setup B: xwrepA(0..17) | xwrepB(18..81)
__global__ __launch_bounds__(256) void k_setupB(const float* wihA, const float* f,
        const float* bihA, const float* bhhA, float* xwA,
        const float* wihB, const float* bihB, const float* bhhB, float* xwB)
{
  __shared__ float Wl[64*129];
  const int bi = blockIdx.x, tid = threadIdx.x;
  if (bi < 18){
    int g0 = bi*64;
    for (int idx = tid; idx < 64*128; idx += 256){
      int gg = idx>>7, c = idx&127;
      Wl[gg*129+c] = wihA[(size_t)(g0+gg)*INA + 768 + c];
    }
    __syncthreads();
    int vv = tid>>6, gg = tid&63; int g = g0+gg;
    float badd = bihA[g] + (g < 768 ? bhhA[g] : 0.f);
    for (int row = vv; row < 64*JREP; row += 4){
      const float* fr = f + (size_t)row*DF;
      float acc = badd;
      for (int c = 0; c < 128; ++c) acc += fr[c]*Wl[gg*129+c];
      xwA[(size_t)row*G3 + g] = acc;
    }
  } else {
    int b = bi - 18;
    for (int idx = tid; idx < 48*128; idx += 256){
      int r = idx>>7, c = idx&127;
      Wl[r*129+c] = wihB[r*512 + 384 + c];
    }
    __syncthreads();
    for (int idx = tid; idx < JREP*48; idx += 256){
      int j = idx/48, r = idx%48;
      const float* fr = f + (size_t)(b*JREP+j)*DF;
      float acc = bihB[r] + (r < 32 ? bhhB[r] : 0.f);
      for (int c = 0; c < 128; ++c) acc += fr[c]*Wl[r*129+c];
      xwB[(size_t)(b*JREP+j)*48 + r] = acc;
    }
  }
}

// ---------------- GRU-A scan v14: R13 + in-scan xwB partials, g1 store removed ----------------
#define LD18(n) uint4 d##n = wsrc[(size_t)(n)*768];
#define Q2(A,B,C, q2) { \
  h2v hA = hh[jb2 + (q2)*2],     hB = hh[jb2 + (q2)*2 + 1]; \
  ar = fdot2_(hA, bc_h2(A.x), ar); ar = fdot2_(hB, bc_h2(A.y), ar); \
  az = fdot2_(hA, bc_h2(A.z), az); az = fdot2_(hB, bc_h2(A.w), az); \
  an = fdot2_(hA, bc_h2(B.x), an); an = fdot2_(hB, bc_h2(B.y), an); \
  h2v hC = hh[jb2 + (q2)*2 + 2], hD = hh[jb2 + (q2)*2 + 3]; \
  ar = fdot2_(hC, bc_h2(B.z), ar); ar = fdot2_(hD, bc_h2(B.w), ar); \
  az = fdot2_(hC, bc_h2(C.x), az); az = fdot2_(hD, bc_h2(C.y), az); \
  an = fdot2_(hC, bc_h2(C.z), an); an = fdot2_(hD, bc_h2(C.w), an); }
#define DOTS12 \
  Q2(d0,d1,d2,0) Q2(d3,d4,d5,2) Q2(d6,d7,d8,4) \
  Q2(d9,d10,d11,6) Q2(d12,d13,d14,8) Q2(d15,d16,d17,10)

#define PL2(na, nb_, p) { u64 w2 = __hip_atomic_load((const u64*)(p), __ATOMIC_RELAXED, __HIP_MEMORY_SCOPE_AGENT); \
  rv##na = (unsigned)w2; rv##nb_ = (unsigned)(w2 >> 32); \
  ok &= ((rv##na & 1023u) == tg) & ((rv##nb_ & 1023u) == tg); }

__global__ __launch_bounds__(768, 3) void k_scanA14(const int* __restrict__ in_data,
        const float* __restrict__ GA, const float* __restrict__ xwA,
        const uint4* __restrict__ wpk, const float* __restrict__ bhh,
        const float* __restrict__ wihB, unsigned* pbuf, float* __restrict__ pxb)
{
  __shared__ __align__(16) unsigned h16u[48];     // own j-quarter h(t-1): 96 rows = 48 u32
  __shared__ __align__(8)  float pg[3][2][384];   // own-quarter partials [gate][u][out-row]
  __shared__ __align__(8)  float xwb[2][G3];      // xW double buffer
  __shared__ __align__(8)  unsigned wlB[48*49];   // gruB wih quarter slice, f16 pairs (padded)
  __shared__ int indr[2][8];
  const int P = blockIdx.x;
  const int b = P & 63, hf = P >> 6;
  const int tid = threadIdx.x;
  const int i  = tid % 384;                       // output row (global)
  const int u  = tid / 384;                       // j-half of own quarter
  const int jb2 = u * 24;                         // h2 base into h16u
  const int* ind_b = in_data + (size_t)b*TT*3;

  // weights: 18 uint4 (j-quarter slice), loaded once
  const uint4* wsrc = wpk + (size_t)(hf*18)*768 + tid;
  LD18(0) LD18(1) LD18(2) LD18(3) LD18(4) LD18(5) LD18(6) LD18(7) LD18(8)
  LD18(9) LD18(10) LD18(11) LD18(12) LD18(13) LD18(14) LD18(15) LD18(16) LD18(17)

  // gruB quarter-slice weights -> LDS (48 rows x 48 f16-pairs, pad 49)
  for (int idx = tid; idx < 48*48; idx += 768){
    int r = idx/48, k = idx%48;
    wlB[r*49+k] = pk2_(wihB[r*512 + hf*96 + 2*k], wihB[r*512 + hf*96 + 2*k + 1]);
  }

  const bool isGat = (tid < 576);
  const int  c0 = 2*tid, c1 = 2*tid + 1;
  const bool isPub = (tid >= 96 && tid < 672);
  const int  po0 = 2*(tid - 96);
  const bool isPxb = (tid >= 48 && tid < 96);
  float* pxbBase = pxb + (size_t)(b*4 + hf)*TS*48 + (tid - 48);

  float hreg0 = 0.f, hreg1 = 0.f, bn0 = 0.f, bn1 = 0.f;
  if (tid < 48){
    bn0 = bhh[768 + hf*96 + 2*tid];
    bn1 = bhh[768 + hf*96 + 2*tid + 1];
    h16u[tid] = 0u;
  }
  // prologue: xwb[0] for t=0 ; indices for t=1
  if (isGat){
    float s0 = xwA[(size_t)(b*JREP)*G3 + c0];
    float s1 = xwA[(size_t)(b*JREP)*G3 + c1];
    #pragma unroll
    for (int k2 = 0; k2 < 6; ++k2){
      int v = ind_b[k2];
      s0 += GA[((size_t)k2*256 + v)*G3 + c0];
      s1 += GA[((size_t)k2*256 + v)*G3 + c1];
    }
    xwb[0][c0] = s0; xwb[0][c1] = s1;
  }
  if (tid >= 576 && tid < 582) indr[1][tid-576] = ind_b[6 + (tid-576)];

  unsigned* pbo = pbuf + ((size_t)(b*4 + hf)*2)*G3;
  const int pf1 = (hf+1)&3, pf2 = (hf+2)&3, pf3 = (hf+3)&3;
  const unsigned* pb1 = pbuf + ((size_t)(b*4 + pf1)*2)*G3 + hf*96 + 2*(tid<48?tid:0);
  const unsigned* pb2 = pbuf + ((size_t)(b*4 + pf2)*2)*G3 + hf*96 + 2*(tid<48?tid:0);
  const unsigned* pb3 = pbuf + ((size_t)(b*4 + pf3)*2)*G3 + hf*96 + 2*(tid<48?tid:0);
  const h2v* hh = (const h2v*)h16u;
  __syncthreads();

  for (int t = 0; t < TS; ++t){
    const int nb = t & 1;
    // ---- phase 1: xW gathers for t+1, dots on OWN h-quarter, gruB partial for t-1 ----
    const int tp = t + 1;
    float ga0=0.f,ga1=0.f,ga2=0.f,ga3=0.f,ga4=0.f,ga5=0.f,gx0=0.f;
    float gb0=0.f,gb1=0.f,gb2=0.f,gb3=0.f,gb4=0.f,gb5=0.f,gx1=0.f;
    if (tp < TS && isGat){
      int v0=indr[tp&1][0], v1=indr[tp&1][1], v2=indr[tp&1][2];
      int v3=indr[tp&1][3], v4=indr[tp&1][4], v5=indr[tp&1][5];
      const float* xwr = xwA + ((size_t)(b*JREP) + tp/80)*G3;
      ga0 = GA[((size_t)0*256 + v0)*G3 + c0]; gb0 = GA[((size_t)0*256 + v0)*G3 + c1];
      ga1 = GA[((size_t)1*256 + v1)*G3 + c0]; gb1 = GA[((size_t)1*256 + v1)*G3 + c1];
      ga2 = GA[((size_t)2*256 + v2)*G3 + c0]; gb2 = GA[((size_t)2*256 + v2)*G3 + c1];
      ga3 = GA[((size_t)3*256 + v3)*G3 + c0]; gb3 = GA[((size_t)3*256 + v3)*G3 + c1];
      ga4 = GA[((size_t)4*256 + v4)*G3 + c0]; gb4 = GA[((size_t)4*256 + v4)*G3 + c1];
      ga5 = GA[((size_t)5*256 + v5)*G3 + c0]; gb5 = GA[((size_t)5*256 + v5)*G3 + c1];
      gx0 = xwr[c0]; gx1 = xwr[c1];
    }
    int iv = 0;
    const int stg = t + 2;
    const bool doStg = (tid >= 576 && tid < 582 && stg < TS);
    if (doStg) iv = ind_b[6*stg + (tid-576)];
    float ar=0.f, az=0.f, an=0.f;
    DOTS12
    pg[0][u][i] = ar; pg[1][u][i] = az; pg[2][u][i] = an;
    // gruB input partial for step t-1: pxb = h16u (= g1[t-1] own quarter) . wlB row
    if (isPxb && t > 0){
      int r = tid - 48;
      float acc = 0.f;
      #pragma unroll 8
      for (int k = 0; k < 48; ++k) acc = fdot2_(hh[k], bc_h2(wlB[r*49+k]), acc);
      pxbBase[(size_t)(t-1)*48] = acc;
    }
    if (tp < TS && isGat){
      xwb[tp&1][c0] = ga0+ga1+ga2+ga3+ga4+ga5+gx0;
      xwb[tp&1][c1] = gb0+gb1+gb2+gb3+gb4+gb5+gx1;
    }
    if (doStg) indr[t&1][tid-576] = iv;
    bar_lgkm();
    // ---- phase 2: publishers push tagged partials; epilogue lanes poll + update h ----
    if (isPub){
      int g = po0/384, ii = po0 - g*384;
      float2 p0 = *(const float2*)&pg[g][0][ii];
      float2 p1 = *(const float2*)&pg[g][1][ii];
      float v0 = p0.x + p1.x, v1 = p0.y + p1.y;
      unsigned tw0 = (__builtin_bit_cast(unsigned, v0) & 0xFFFFFC00u) | (unsigned)(t & 1023);
      unsigned tw1 = (__builtin_bit_cast(unsigned, v1) & 0xFFFFFC00u) | (unsigned)(t & 1023);
      unsigned* dst = pbo + (size_t)nb*G3 + po0;
      __hip_atomic_store(dst,     tw0, __ATOMIC_RELAXED, __HIP_MEMORY_SCOPE_AGENT);
      __hip_atomic_store(dst + 1, tw1, __ATOMIC_RELAXED, __HIP_MEMORY_SCOPE_AGENT);
    } else if (tid < 48){
      const unsigned tg = (unsigned)t & 1023u;
      const unsigned* q1 = pb1 + (size_t)nb*G3;
      const unsigned* q2 = pb2 + (size_t)nb*G3;
      const unsigned* q3 = pb3 + (size_t)nb*G3;
      unsigned rv0,rv1,rv2,rv3,rv4,rv5,rv6,rv7,rv8;
      unsigned rv9,rv10,rv11,rv12,rv13,rv14,rv15,rv16,rv17;
      bool ok;
      do {
        ok = true;
        PL2(0,1,   q1+0) PL2(2,3,   q1+384) PL2(4,5,   q1+768)
        PL2(6,7,   q2+0) PL2(8,9,   q2+384) PL2(10,11, q2+768)
        PL2(12,13, q3+0) PL2(14,15, q3+384) PL2(16,17, q3+768)
        if (!ok) __builtin_amdgcn_s_sleep(1);
      } while (!ok);
      __builtin_amdgcn_sched_barrier(0);
      #define FV(n) __builtin_bit_cast(float, rv##n & 0xFFFFFC00u)
      int i0 = hf*96 + 2*tid;
      float2 o0 = *(const float2*)&pg[0][0][i0];  float2 o0b = *(const float2*)&pg[0][1][i0];
      float2 o1 = *(const float2*)&pg[1][0][i0];  float2 o1b = *(const float2*)&pg[1][1][i0];
      float2 o2 = *(const float2*)&pg[2][0][i0];  float2 o2b = *(const float2*)&pg[2][1][i0];
      float2 xr = *(const float2*)&xwb[nb][i0];
      float2 xz = *(const float2*)&xwb[nb][384 + i0];
      float2 xn = *(const float2*)&xwb[nb][768 + i0];
      float R0 = o0.x + o0b.x + FV(0)  + FV(6)  + FV(12) + xr.x;
      float R1 = o0.y + o0b.y + FV(1)  + FV(7)  + FV(13) + xr.y;
      float Z0 = o1.x + o1b.x + FV(2)  + FV(8)  + FV(14) + xz.x;
      float Z1 = o1.y + o1b.y + FV(3)  + FV(9)  + FV(15) + xz.y;
      float G0 = o2.x + o2b.x + FV(4)  + FV(10) + FV(16) + bn0;
      float G1 = o2.y + o2b.y + FV(5)  + FV(11) + FV(17) + bn1;
      #undef FV
      float rr0 = sigmf_(R0), zz0 = sigmf_(Z0);
      float nn0 = tanhf_(xn.x + rr0*G0);
      float h0 = (1.f - zz0)*nn0 + zz0*hreg0; hreg0 = h0;
      float rr1 = sigmf_(R1), zz1 = sigmf_(Z1);
      float nn1 = tanhf_(xn.y + rr1*G1);
      float h1 = (1.f - zz1)*nn1 + zz1*hreg1; hreg1 = h1;
      h16u[tid] = pk2_(h0, h1);
    }
    bar_lgkm();
  }
  // tail: gruB partial for t = TS-1 (h16u now holds h(TS-1))
  if (isPxb){
    int r = tid - 48;
    float acc = 0.f;
    #pragma unroll 8
    for (int k = 0; k < 48; ++k) acc = fdot2_(hh[k], bc_h2(wlB[r*49+k]), acc);
    pxbBase[(size_t)(TS-1)*48] = acc;
  }
}

// ---------------- GRU-B scan: single-wave shuffle; xwB = sum of 4 in-scan partials + xwrB --------
__global__ __launch_bounds__(64) void k_scanB(const float* pxb, const float* xwrB,
                                              const float* whh, const float* bhh, float* g2){
  int b = blockIdx.x, tid = threadIdx.x;
  float w0=0,w1=0,w2=0,w3=0,w4=0,w5=0,w6=0,w7=0;
  float w8=0,w9=0,w10=0,w11=0,w12=0,w13=0,w14=0,w15=0;
  if (tid < 48){
    const float* wr = whh + tid*16;
    w0=wr[0];w1=wr[1];w2=wr[2];w3=wr[3];w4=wr[4];w5=wr[5];w6=wr[6];w7=wr[7];
    w8=wr[8];w9=wr[9];w10=wr[10];w11=wr[11];w12=wr[12];w13=wr[13];w14=wr[14];w15=wr[15];
  }
  float bng = (tid < 16) ? bhh[32 + tid] : 0.f;
  const float* p0 = pxb + (size_t)(b*4+0)*TS*48 + tid;
  const float* p1 = pxb + (size_t)(b*4+1)*TS*48 + tid;
  const float* p2 = pxb + (size_t)(b*4+2)*TS*48 + tid;
  const float* p3 = pxb + (size_t)(b*4+3)*TS*48 + tid;
  const float* xr = xwrB + (size_t)(b*JREP)*48 + tid;
  float hv = 0.f;
  float xw_n = 0.f;
  if (tid < 48) xw_n = p0[0] + p1[0] + p2[0] + p3[0] + xr[0];
  for (int t = 0; t < TS; ++t){
    float xw = xw_n;
    if (t+1 < TS && tid < 48)
      xw_n = p0[(size_t)(t+1)*48] + p1[(size_t)(t+1)*48] + p2[(size_t)(t+1)*48]
           + p3[(size_t)(t+1)*48] + xr[(size_t)((t+1)/80)*48];
    float gh = 0.f;
    gh += w0 *__shfl(hv, 0, 64);  gh += w1 *__shfl(hv, 1, 64);
    gh += w2 *__shfl(hv, 2, 64);  gh += w3 *__shfl(hv, 3, 64);
    gh += w4 *__shfl(hv, 4, 64);  gh += w5 *__shfl(hv, 5, 64);
    gh += w6 *__shfl(hv, 6, 64);  gh += w7 *__shfl(hv, 7, 64);
    gh += w8 *__shfl(hv, 8, 64);  gh += w9 *__shfl(hv, 9, 64);
    gh += w10*__shfl(hv,10, 64);  gh += w11*__shfl(hv,11, 64);
    gh += w12*__shfl(hv,12, 64);  gh += w13*__shfl(hv,13, 64);
    gh += w14*__shfl(hv,14, 64);  gh += w15*__shfl(hv,15, 64);
    float val = xw + gh;
    float zv  = __shfl(val, (tid+16) & 63, 64);
    float xn_ = __shfl(xw,  (tid+32) & 63, 64);
    float gn_ = __shfl(gh,  (tid+32) & 63, 64) + bng;
    if (tid < 16){
      float r = sigmf_(val), z = sigmf_(zv);
      float n = tanhf_(xn_ + r*gn_);
      hv = (1.f - z)*n + z*hv;
      g2[((size_t)b*TS + t)*16 + tid] = hv;
    }
  }
}

// ---------------- mdense + output interleave ----------------
__global__ __launch_bounds__(256) void k_out(const float* g2, const int* targets, const float* T2,
    const float* m1w1, const float* m1w2, const float* m1b1, const float* m1b2,
    const float* m1f1, const float* m1f2,
    const float* m2w1, const float* m2w2, const float* m2b1, const float* m2b2,
    const float* m2f1, const float* m2f2, float* out)
{
  __shared__ float wA[256*17], wB[256*17], wC[256*17], wD[256*17];
  __shared__ float g2l[16*16];
  int bi = blockIdx.x; int b = bi/55; int t0 = (bi%55)*16; int c = threadIdx.x;
  for (int d = 0; d < 16; ++d){
    wA[c*17+d] = m1w1[c*16+d];  wB[c*17+d] = m1w2[c*16+d];
    wC[c*17+d] = m2w1[c*144+d]; wD[c*17+d] = m2w2[c*144+d];
  }
  { int tt = c>>4, d = c&15; g2l[c] = g2[((size_t)b*TS + t0+tt)*16 + d]; }
  __syncthreads();
  float b1a = m1b1[c], b2a = m1b2[c], f1a = m1f1[c], f2a = m1f2[c];
  float b1b = m2b1[c], b2b = m2b2[c], f1b = m2f1[c], f2b = m2f2[c];
  for (int tt = 0; tt < 16; ++tt){
    int t = t0+tt;
    float d1 = b1a, d2 = b2a, e1 = b1b, e2 = b2b;
    for (int d = 0; d < 16; ++d){
      float g = g2l[tt*16+d];
      d1 += g*wA[c*17+d]; d2 += g*wB[c*17+d];
      e1 += g*wC[c*17+d]; e2 += g*wD[c*17+d];
    }
    int v = targets[b*TT + 2*t];
    e1 += T2[v*256+c]; e2 += T2[65536 + v*256+c];
    float o1 = f1a*tanhf_(d1) + f2a*tanhf_(d2);
    float o2 = f1b*tanhf_(e1) + f2b*tanhf_(e2);
    size_t base = ((size_t)b*TS + t)*2*256;
    out[base + c]       = o1;
    out[base + 256 + c] = o2;
  }
}

extern "C" void kernel_launch(void* const* d_in, const int* in_sizes, int n_in,
                              void* d_out, int out_size, void* d_ws, size_t ws_size,
                              hipStream_t stream) {
  const int*   in_data = (const int*)  d_in[0];
  const float* feat    = (const float*)d_in[1];
  const int*   periods = (const int*)  d_in[2];
  const int*   targets = (const int*)  d_in[3];
  const float* embp    = (const float*)d_in[4];
  const float* embs    = (const float*)d_in[5];
  const float* c1w = (const float*)d_in[6];  const float* c1b = (const float*)d_in[7];
  const float* c2w = (const float*)d_in[8];  const float* c2b = (const float*)d_in[9];
  const float* f1w = (const float*)d_in[10]; const float* f1b = (const float*)d_in[11];
  const float* f2w = (const float*)d_in[12]; const float* f2b = (const float*)d_in[13];
  const float* ga_wih = (const float*)d_in[14]; const float* ga_whh = (const float*)d_in[15];
  const float* ga_bih = (const float*)d_in[16]; const float* ga_bhh = (const float*)d_in[17];
  const float* gb_wih = (const float*)d_in[18]; const float* gb_whh = (const float*)d_in[19];
  const float* gb_bih = (const float*)d_in[20]; const float* gb_bhh = (const float*)d_in[21];
  const float* m1w1 = (const float*)d_in[22]; const float* m1w2 = (const float*)d_in[23];
  const float* m1b1 = (const float*)d_in[24]; const float* m1b2 = (const float*)d_in[25];
  const float* m1f1 = (const float*)d_in[26]; const float* m1f2 = (const float*)d_in[27];
  const float* m2w1 = (const float*)d_in[28]; const float* m2w2 = (const float*)d_in[29];
  const float* m2b1 = (const float*)d_in[30]; const float* m2b2 = (const float*)d_in[31];
  const float* m2f1 = (const float*)d_in[32]; const float* m2f2 = (const float*)d_in[33];
  float* out = (float*)d_out;

  // workspace layout (floats)
  float* GA     = (float*)d_ws;                  // 6*256*1152     = 1,769,472
  float* xWrepA = GA     + 1769472;              // 704*1152       =   811,008
  float* xWrepB = xWrepA + 811008;               // 704*48         =    33,792
  float* fbuf   = xWrepB + 33792;                // 704*128        =    90,112
  float* g2buf  = fbuf   + 90112;                // 56320*16       =   901,120
  float* T2     = g2buf  + 901120;               // 2*256*256      =   131,072
  _Float16* Wpk = (_Float16*)(T2 + 131072);      // 442,368 halves
  unsigned* pbuf = (unsigned*)(Wpk + 442368);    // 64*4*2*1152 u32 = 589,824
  float* pxb    = (float*)d_out;                 // 64*4*880*48 = 10,813,440 floats (43MB < 115MB),
                                                 // dead before k_out overwrites d_out

  (void)hipMemsetAsync(pbuf, 0xFF, 589824*sizeof(unsigned), stream);
  hipLaunchKernelGGL(k_setupA, dim3(1908), dim3(256), 0, stream,
                     feat, periods, embp, c1w, c1b, c2w, c2b, f1w, f1b, f2w, f2b, fbuf,
                     ga_whh, Wpk, ga_wih, embs, GA, m2w1, m2w2, T2);
  hipLaunchKernelGGL(k_setupB, dim3(82), dim3(256), 0, stream,
                     ga_wih, fbuf, ga_bih, ga_bhh, xWrepA,
                     gb_wih, gb_bih, gb_bhh, xWrepB);
  hipLaunchKernelGGL(k_scanA14, dim3(256), dim3(768), 0, stream,
                     in_data, GA, xWrepA, (const uint4*)Wpk, ga_bhh,
                     gb_wih, pbuf, pxb);
  hipLaunchKernelGGL(k_scanB, dim3(64), dim3(64), 0, stream,
                     pxb, xWrepB, gb_whh, gb_bhh, g2buf);
  hipLaunchKernelGGL(k_out, dim3(64*55), dim3(256), 0, stream,
                     g2buf, targets, T2, m1w1, m1w2, m1b1, m1b2, m1f1, m1f2,
                     m2w1, m2w2, m2b1, m2b2, m2f1, m2f2, out);
}

// Round 15
// 3397.803 us; speedup vs baseline: 2.7573x; 1.0681x over previous
//
#include <hip/hip_runtime.h>
#include <hip/hip_bf16.h>
#include <hip/hip_fp16.h>

#define NF    15
#define NBF   20
#define TT    1760
#define TS    880
#define EP    64
#define ES    128
#define DF    128
#define H1    384
#define G3    1152
#define INA   896
#define JREP  11

typedef _Float16 h2v __attribute__((ext_vector_type(2)));
typedef unsigned long long u64;

__device__ __forceinline__ float sigmf_(float x){ return 1.0f/(1.0f + __expf(-x)); }
__device__ __forceinline__ float tanhf_(float x){ return 2.0f/(1.0f + __expf(-2.0f*x)) - 1.0f; }
__device__ __forceinline__ h2v bc_h2(unsigned u){ return __builtin_bit_cast(h2v, u); }
__device__ __forceinline__ float fdot2_(h2v a, h2v b, float c){
#if __has_builtin(__builtin_amdgcn_fdot2)
  return __builtin_amdgcn_fdot2(a, b, c, false);
#else
  return c + (float)a[0]*(float)b[0] + (float)a[1]*(float)b[1];
#endif
}
__device__ __forceinline__ unsigned pk2_(float a, float b){
#if __has_builtin(__builtin_amdgcn_cvt_pkrtz)
  return __builtin_bit_cast(unsigned, __builtin_amdgcn_cvt_pkrtz(a, b));
#else
  unsigned lo = (unsigned)__builtin_bit_cast(unsigned short, (_Float16)a);
  unsigned hi = (unsigned)__builtin_bit_cast(unsigned short, (_Float16)b);
  return lo | (hi << 16);
#endif
}
__device__ __forceinline__ void bar_lgkm(){
  asm volatile("s_waitcnt lgkmcnt(0)" ::: "memory");
  __builtin_amdgcn_s_barrier();
  __builtin_amdgcn_sched_barrier(0);
}

// ============ fused setup A: frame(0..63) | wpack5(64..1791) | tables(1792..1899) | t2(1900..1907)
__global__ __launch_bounds__(256) void k_setupA(const float* feat, const int* periods, const float* embp,
   const float* c1w, const float* c1b, const float* c2w, const float* c2b,
   const float* f1w, const float* f1b, const float* f2w, const float* f2b, float* fout,
   const float* whh, _Float16* wpk,
   const float* wih, const float* emb, float* GA,
   const float* m2w1, const float* m2w2, float* T2)
{
  __shared__ float sh[8256];
  const int bi = blockIdx.x, tid = threadIdx.x;
  if (bi < 64){
    float* cat = sh;            // 15*84 = 1260
    float* x1  = sh + 1260;     // 13*128 = 1664
    float* x2  = sh + 2924;     // 11*128 = 1408
    int b = bi;
    for (int idx = tid; idx < NF*84; idx += 256){
      int j = idx/84, c = idx%84;
      cat[idx] = (c < NBF) ? feat[(b*NF+j)*NBF + c]
                           : embp[periods[b*NF+j]*EP + (c-NBF)];
    }
    __syncthreads();
    int o = tid;
    if (o < DF){
      for (int p = 0; p < 13; ++p){
        float acc = c1b[o];
        for (int kk = 0; kk < 3; ++kk)
          for (int c = 0; c < 84; ++c)
            acc += cat[(p+kk)*84 + c] * c1w[(o*84+c)*3+kk];
        x1[p*DF+o] = tanhf_(acc);
      }
    }
    __syncthreads();
    if (o < DF){
      for (int p = 0; p < JREP; ++p){
        float acc = c2b[o];
        for (int kk = 0; kk < 3; ++kk)
          for (int c = 0; c < DF; ++c)
            acc += x1[(p+kk)*DF+c] * c2w[(o*DF+c)*3+kk];
        x2[p*DF+o] = tanhf_(acc);
      }
    }
    __syncthreads();
    if (o < DF){
      for (int p = 0; p < JREP; ++p){
        float acc = f1b[o];
        for (int c = 0; c < DF; ++c) acc += x2[p*DF+c]*f1w[o*DF+c];
        x1[p*DF+o] = tanhf_(acc);
      }
    }
    __syncthreads();
    if (o < DF){
      for (int p = 0; p < JREP; ++p){
        float acc = f2b[o];
        for (int c = 0; c < DF; ++c) acc += x1[p*DF+c]*f2w[o*DF+c];
        fout[(b*JREP+p)*DF+o] = tanhf_(acc);
      }
    }
  } else if (bi < 1792){
    int o = (bi-64)*256 + tid;                   // < 442368
    int hu = o & 1;
    int c  = (o >> 1) & 3;
    int idx = o >> 3;
    int t768 = idx % 768;
    int n    = (idx / 768) % 18;
    int hf   = idx / (768*18);
    int i = t768 % 384, u = t768 / 384;
    int gd = n*4 + c;
    int m = gd / 12, dc = gd % 12;
    int pos  = (dc % 2) + 2*(dc / 6);
    int gate = (dc % 6) >> 1;
    int j = hf*96 + u*48 + (4*m + pos)*2 + hu;
    wpk[o] = (_Float16)whh[(gate*H1 + i)*H1 + j];
  } else if (bi < 1900){
    float* Wl = sh;
    int bb = bi - 1792;
    int k = bb/18, g0 = (bb%18)*64;
    for (int idx = tid; idx < 64*128; idx += 256){
      int gg = idx>>7, c = idx&127;
      Wl[gg*129+c] = wih[(size_t)(g0+gg)*INA + k*128 + c];
    }
    __syncthreads();
    int vv = tid>>6, gg = tid&63;
    for (int v = vv; v < 256; v += 4){
      const float* e = emb + (size_t)v*ES;
      float acc = 0.f;
      for (int c = 0; c < 128; ++c) acc += e[c]*Wl[gg*129+c];
      GA[(size_t)(k*256+v)*G3 + g0+gg] = acc;
    }
  } else {
    float* Wl = sh;
    int bb = bi - 1900;
    int tbl = bb>>2; int c0 = (bb&3)*64;
    const float* w = tbl ? m2w2 : m2w1;
    for (int idx = tid; idx < 64*128; idx += 256){
      int cc = idx>>7, e = idx&127;
      Wl[cc*129+e] = w[(c0+cc)*144 + 16 + e];
    }
    __syncthreads();
    int vv = tid>>6, cc = tid&63;
    for (int v = vv; v < 256; v += 4){
      const float* e = emb + (size_t)v*ES;
      float acc = 0.f;
      for (int c = 0; c < 128; ++c) acc += e[c]*Wl[cc*129+c];
      T2[tbl*65536 + v*256 + c0+cc] = acc;
    }
  }
}

// ============ fused setup B: xwrepA(0..17) | xwrepB(18..81)
__global__ __launch_bounds__(256) void k_setupB(const float* wihA, const float* f,
        const float* bihA, const float* bhhA, float* xwA,
        const float* wihB, const float* bihB, const float* bhhB, float* xwB)
{
  __shared__ float Wl[64*129];
  const int bi = blockIdx.x, tid = threadIdx.x;
  if (bi < 18){
    int g0 = bi*64;
    for (int idx = tid; idx < 64*128; idx += 256){
      int gg = idx>>7, c = idx&127;
      Wl[gg*129+c] = wihA[(size_t)(g0+gg)*INA + 768 + c];
    }
    __syncthreads();
    int vv = tid>>6, gg = tid&63; int g = g0+gg;
    float badd = bihA[g] + (g < 768 ? bhhA[g] : 0.f);
    for (int row = vv; row < 64*JREP; row += 4){
      const float* fr = f + (size_t)row*DF;
      float acc = badd;
      for (int c = 0; c < 128; ++c) acc += fr[c]*Wl[gg*129+c];
      xwA[(size_t)row*G3 + g] = acc;
    }
  } else {
    int b = bi - 18;
    for (int idx = tid; idx < 48*128; idx += 256){
      int r = idx>>7, c = idx&127;
      Wl[r*129+c] = wihB[r*512 + 384 + c];
    }
    __syncthreads();
    for (int idx = tid; idx < JREP*48; idx += 256){
      int j = idx/48, r = idx%48;
      const float* fr = f + (size_t)(b*JREP+j)*DF;
      float acc = bihB[r] + (r < 32 ? bhhB[r] : 0.f);
      for (int c = 0; c < 128; ++c) acc += fr[c]*Wl[r*129+c];
      xwB[(size_t)(b*JREP+j)*48 + r] = acc;
    }
  }
}

// ---------------- GRU-A scan v14: R13 + in-scan xwB partials ----------------
#define LD18(n) uint4 d##n = wsrc[(size_t)(n)*768];
#define Q2(A,B,C, q2) { \
  h2v hA = hh[jb2 + (q2)*2],     hB = hh[jb2 + (q2)*2 + 1]; \
  ar = fdot2_(hA, bc_h2(A.x), ar); ar = fdot2_(hB, bc_h2(A.y), ar); \
  az = fdot2_(hA, bc_h2(A.z), az); az = fdot2_(hB, bc_h2(A.w), az); \
  an = fdot2_(hA, bc_h2(B.x), an); an = fdot2_(hB, bc_h2(B.y), an); \
  h2v hC = hh[jb2 + (q2)*2 + 2], hD = hh[jb2 + (q2)*2 + 3]; \
  ar = fdot2_(hC, bc_h2(B.z), ar); ar = fdot2_(hD, bc_h2(B.w), ar); \
  az = fdot2_(hC, bc_h2(C.x), az); az = fdot2_(hD, bc_h2(C.y), az); \
  an = fdot2_(hC, bc_h2(C.z), an); an = fdot2_(hD, bc_h2(C.w), an); }
#define DOTS12 \
  Q2(d0,d1,d2,0) Q2(d3,d4,d5,2) Q2(d6,d7,d8,4) \
  Q2(d9,d10,d11,6) Q2(d12,d13,d14,8) Q2(d15,d16,d17,10)

#define PL2(na, nb_, p) { u64 w2 = __hip_atomic_load((const u64*)(p), __ATOMIC_RELAXED, __HIP_MEMORY_SCOPE_AGENT); \
  rv##na = (unsigned)w2; rv##nb_ = (unsigned)(w2 >> 32); \
  ok &= ((rv##na & 1023u) == tg) & ((rv##nb_ & 1023u) == tg); }

__global__ __launch_bounds__(768, 3) void k_scanA14(const int* __restrict__ in_data,
        const float* __restrict__ GA, const float* __restrict__ xwA,
        const uint4* __restrict__ wpk, const float* __restrict__ bhh,
        const float* __restrict__ wihB, unsigned* pbuf, float* __restrict__ pxb)
{
  __shared__ __align__(16) unsigned h16u[48];     // own j-quarter h(t-1): 96 rows = 48 u32
  __shared__ __align__(8)  float pg[3][2][384];   // own-quarter partials [gate][u][out-row]
  __shared__ __align__(8)  float xwb[2][G3];      // xW double buffer
  __shared__ __align__(8)  unsigned wlB[48*49];   // gruB wih quarter slice, f16 pairs (padded)
  __shared__ int indr[2][8];
  const int P = blockIdx.x;
  const int b = P & 63, hf = P >> 6;
  const int tid = threadIdx.x;
  const int i  = tid % 384;
  const int u  = tid / 384;
  const int jb2 = u * 24;
  const int* ind_b = in_data + (size_t)b*TT*3;

  const uint4* wsrc = wpk + (size_t)(hf*18)*768 + tid;
  LD18(0) LD18(1) LD18(2) LD18(3) LD18(4) LD18(5) LD18(6) LD18(7) LD18(8)
  LD18(9) LD18(10) LD18(11) LD18(12) LD18(13) LD18(14) LD18(15) LD18(16) LD18(17)

  for (int idx = tid; idx < 48*48; idx += 768){
    int r = idx/48, k = idx%48;
    wlB[r*49+k] = pk2_(wihB[r*512 + hf*96 + 2*k], wihB[r*512 + hf*96 + 2*k + 1]);
  }

  const bool isGat = (tid < 576);
  const int  c0 = 2*tid, c1 = 2*tid + 1;
  const bool isPub = (tid >= 96 && tid < 672);
  const int  po0 = 2*(tid - 96);
  const bool isPxb = (tid >= 48 && tid < 96);
  float* pxbBase = pxb + (size_t)(b*4 + hf)*TS*48 + (tid - 48);

  float hreg0 = 0.f, hreg1 = 0.f, bn0 = 0.f, bn1 = 0.f;
  if (tid < 48){
    bn0 = bhh[768 + hf*96 + 2*tid];
    bn1 = bhh[768 + hf*96 + 2*tid + 1];
    h16u[tid] = 0u;
  }
  if (isGat){
    float s0 = xwA[(size_t)(b*JREP)*G3 + c0];
    float s1 = xwA[(size_t)(b*JREP)*G3 + c1];
    #pragma unroll
    for (int k2 = 0; k2 < 6; ++k2){
      int v = ind_b[k2];
      s0 += GA[((size_t)k2*256 + v)*G3 + c0];
      s1 += GA[((size_t)k2*256 + v)*G3 + c1];
    }
    xwb[0][c0] = s0; xwb[0][c1] = s1;
  }
  if (tid >= 576 && tid < 582) indr[1][tid-576] = ind_b[6 + (tid-576)];

  unsigned* pbo = pbuf + ((size_t)(b*4 + hf)*2)*G3;
  const int pf1 = (hf+1)&3, pf2 = (hf+2)&3, pf3 = (hf+3)&3;
  const unsigned* pb1 = pbuf + ((size_t)(b*4 + pf1)*2)*G3 + hf*96 + 2*(tid<48?tid:0);
  const unsigned* pb2 = pbuf + ((size_t)(b*4 + pf2)*2)*G3 + hf*96 + 2*(tid<48?tid:0);
  const unsigned* pb3 = pbuf + ((size_t)(b*4 + pf3)*2)*G3 + hf*96 + 2*(tid<48?tid:0);
  const h2v* hh = (const h2v*)h16u;
  __syncthreads();

  for (int t = 0; t < TS; ++t){
    const int nb = t & 1;
    const int tp = t + 1;
    float ga0=0.f,ga1=0.f,ga2=0.f,ga3=0.f,ga4=0.f,ga5=0.f,gx0=0.f;
    float gb0=0.f,gb1=0.f,gb2=0.f,gb3=0.f,gb4=0.f,gb5=0.f,gx1=0.f;
    if (tp < TS && isGat){
      int v0=indr[tp&1][0], v1=indr[tp&1][1], v2=indr[tp&1][2];
      int v3=indr[tp&1][3], v4=indr[tp&1][4], v5=indr[tp&1][5];
      const float* xwr = xwA + ((size_t)(b*JREP) + tp/80)*G3;
      ga0 = GA[((size_t)0*256 + v0)*G3 + c0]; gb0 = GA[((size_t)0*256 + v0)*G3 + c1];
      ga1 = GA[((size_t)1*256 + v1)*G3 + c0]; gb1 = GA[((size_t)1*256 + v1)*G3 + c1];
      ga2 = GA[((size_t)2*256 + v2)*G3 + c0]; gb2 = GA[((size_t)2*256 + v2)*G3 + c1];
      ga3 = GA[((size_t)3*256 + v3)*G3 + c0]; gb3 = GA[((size_t)3*256 + v3)*G3 + c1];
      ga4 = GA[((size_t)4*256 + v4)*G3 + c0]; gb4 = GA[((size_t)4*256 + v4)*G3 + c1];
      ga5 = GA[((size_t)5*256 + v5)*G3 + c0]; gb5 = GA[((size_t)5*256 + v5)*G3 + c1];
      gx0 = xwr[c0]; gx1 = xwr[c1];
    }
    int iv = 0;
    const int stg = t + 2;
    const bool doStg = (tid >= 576 && tid < 582 && stg < TS);
    if (doStg) iv = ind_b[6*stg + (tid-576)];
    float ar=0.f, az=0.f, an=0.f;
    DOTS12
    pg[0][u][i] = ar; pg[1][u][i] = az; pg[2][u][i] = an;
    if (isPxb && t > 0){
      int r = tid - 48;
      float acc = 0.f;
      #pragma unroll 8
      for (int k = 0; k < 48; ++k) acc = fdot2_(hh[k], bc_h2(wlB[r*49+k]), acc);
      pxbBase[(size_t)(t-1)*48] = acc;
    }
    if (tp < TS && isGat){
      xwb[tp&1][c0] = ga0+ga1+ga2+ga3+ga4+ga5+gx0;
      xwb[tp&1][c1] = gb0+gb1+gb2+gb3+gb4+gb5+gx1;
    }
    if (doStg) indr[t&1][tid-576] = iv;
    bar_lgkm();
    if (isPub){
      int g = po0/384, ii = po0 - g*384;
      float2 p0 = *(const float2*)&pg[g][0][ii];
      float2 p1 = *(const float2*)&pg[g][1][ii];
      float v0 = p0.x + p1.x, v1 = p0.y + p1.y;
      unsigned tw0 = (__builtin_bit_cast(unsigned, v0) & 0xFFFFFC00u) | (unsigned)(t & 1023);
      unsigned tw1 = (__builtin_bit_cast(unsigned, v1) & 0xFFFFFC00u) | (unsigned)(t & 1023);
      unsigned* dst = pbo + (size_t)nb*G3 + po0;
      __hip_atomic_store(dst,     tw0, __ATOMIC_RELAXED, __HIP_MEMORY_SCOPE_AGENT);
      __hip_atomic_store(dst + 1, tw1, __ATOMIC_RELAXED, __HIP_MEMORY_SCOPE_AGENT);
    } else if (tid < 48){
      const unsigned tg = (unsigned)t & 1023u;
      const unsigned* q1 = pb1 + (size_t)nb*G3;
      const unsigned* q2 = pb2 + (size_t)nb*G3;
      const unsigned* q3 = pb3 + (size_t)nb*G3;
      unsigned rv0,rv1,rv2,rv3,rv4,rv5,rv6,rv7,rv8;
      unsigned rv9,rv10,rv11,rv12,rv13,rv14,rv15,rv16,rv17;
      bool ok;
      do {
        ok = true;
        PL2(0,1,   q1+0) PL2(2,3,   q1+384) PL2(4,5,   q1+768)
        PL2(6,7,   q2+0) PL2(8,9,   q2+384) PL2(10,11, q2+768)
        PL2(12,13, q3+0) PL2(14,15, q3+384) PL2(16,17, q3+768)
        if (!ok) __builtin_amdgcn_s_sleep(1);
      } while (!ok);
      __builtin_amdgcn_sched_barrier(0);
      #define FV(n) __builtin_bit_cast(float, rv##n & 0xFFFFFC00u)
      int i0 = hf*96 + 2*tid;
      float2 o0 = *(const float2*)&pg[0][0][i0];  float2 o0b = *(const float2*)&pg[0][1][i0];
      float2 o1 = *(const float2*)&pg[1][0][i0];  float2 o1b = *(const float2*)&pg[1][1][i0];
      float2 o2 = *(const float2*)&pg[2][0][i0];  float2 o2b = *(const float2*)&pg[2][1][i0];
      float2 xr = *(const float2*)&xwb[nb][i0];
      float2 xz = *(const float2*)&xwb[nb][384 + i0];
      float2 xn = *(const float2*)&xwb[nb][768 + i0];
      float R0 = o0.x + o0b.x + FV(0)  + FV(6)  + FV(12) + xr.x;
      float R1 = o0.y + o0b.y + FV(1)  + FV(7)  + FV(13) + xr.y;
      float Z0 = o1.x + o1b.x + FV(2)  + FV(8)  + FV(14) + xz.x;
      float Z1 = o1.y + o1b.y + FV(3)  + FV(9)  + FV(15) + xz.y;
      float G0 = o2.x + o2b.x + FV(4)  + FV(10) + FV(16) + bn0;
      float G1 = o2.y + o2b.y + FV(5)  + FV(11) + FV(17) + bn1;
      #undef FV
      float rr0 = sigmf_(R0), zz0 = sigmf_(Z0);
      float nn0 = tanhf_(xn.x + rr0*G0);
      float h0 = (1.f - zz0)*nn0 + zz0*hreg0; hreg0 = h0;
      float rr1 = sigmf_(R1), zz1 = sigmf_(Z1);
      float nn1 = tanhf_(xn.y + rr1*G1);
      float h1 = (1.f - zz1)*nn1 + zz1*hreg1; hreg1 = h1;
      h16u[tid] = pk2_(h0, h1);
    }
    bar_lgkm();
  }
  if (isPxb){
    int r = tid - 48;
    float acc = 0.f;
    #pragma unroll 8
    for (int k = 0; k < 48; ++k) acc = fdot2_(hh[k], bc_h2(wlB[r*49+k]), acc);
    pxbBase[(size_t)(TS-1)*48] = acc;
  }
}

// ---------------- sum partials: xwBs[b][t][48] = sum_q pxb[q] + xwrepB ----------------
__global__ __launch_bounds__(256) void k_sumB(const float* pxb, const float* xwrB, float* xwBs){
  int bi = blockIdx.x;            // 64*11 = 704 blocks: (b, frame j)
  int b = bi / JREP, j = bi % JREP;
  int tid = threadIdx.x;
  const float* p0 = pxb + (size_t)(b*4+0)*TS*48 + (size_t)j*80*48;
  const float* p1 = pxb + (size_t)(b*4+1)*TS*48 + (size_t)j*80*48;
  const float* p2 = pxb + (size_t)(b*4+2)*TS*48 + (size_t)j*80*48;
  const float* p3 = pxb + (size_t)(b*4+3)*TS*48 + (size_t)j*80*48;
  const float* xr = xwrB + (size_t)(b*JREP + j)*48;
  float* dst = xwBs + (size_t)b*TS*48 + (size_t)j*80*48;
  for (int idx = tid; idx < 80*48; idx += 256){
    int r = idx % 48;
    dst[idx] = p0[idx] + p1[idx] + p2[idx] + p3[idx] + xr[r];
  }
}

// ---------------- GRU-B scan: single-wave shuffle, 8-deep prefetch of single stream ------------
__global__ __launch_bounds__(64) void k_scanB(const float* xwBs, const float* whh,
                                              const float* bhh, float* g2){
  int b = blockIdx.x, tid = threadIdx.x;
  float w0=0,w1=0,w2=0,w3=0,w4=0,w5=0,w6=0,w7=0;
  float w8=0,w9=0,w10=0,w11=0,w12=0,w13=0,w14=0,w15=0;
  if (tid < 48){
    const float* wr = whh + tid*16;
    w0=wr[0];w1=wr[1];w2=wr[2];w3=wr[3];w4=wr[4];w5=wr[5];w6=wr[6];w7=wr[7];
    w8=wr[8];w9=wr[9];w10=wr[10];w11=wr[11];w12=wr[12];w13=wr[13];w14=wr[14];w15=wr[15];
  }
  float bng = (tid < 16) ? bhh[32 + tid] : 0.f;
  const float* src = xwBs + (size_t)b*TS*48 + tid;
  float hv = 0.f;
  // 8-deep named prefetch pipeline (rule #20: no runtime-indexed arrays)
  float f0=0,f1=0,f2=0,f3=0,f4=0,f5=0,f6=0,f7=0;
  if (tid < 48){
    f0 = src[0*48]; f1 = src[1*48]; f2 = src[2*48]; f3 = src[3*48];
    f4 = src[4*48]; f5 = src[5*48]; f6 = src[6*48]; f7 = src[7*48];
  }
  for (int t = 0; t < TS; ++t){
    float xw = f0;
    f0=f1; f1=f2; f2=f3; f3=f4; f4=f5; f5=f6; f6=f7;
    if (t+8 < TS && tid < 48) f7 = src[(size_t)(t+8)*48];
    float gh = 0.f;
    gh += w0 *__shfl(hv, 0, 64);  gh += w1 *__shfl(hv, 1, 64);
    gh += w2 *__shfl(hv, 2, 64);  gh += w3 *__shfl(hv, 3, 64);
    gh += w4 *__shfl(hv, 4, 64);  gh += w5 *__shfl(hv, 5, 64);
    gh += w6 *__shfl(hv, 6, 64);  gh += w7 *__shfl(hv, 7, 64);
    gh += w8 *__shfl(hv, 8, 64);  gh += w9 *__shfl(hv, 9, 64);
    gh += w10*__shfl(hv,10, 64);  gh += w11*__shfl(hv,11, 64);
    gh += w12*__shfl(hv,12, 64);  gh += w13*__shfl(hv,13, 64);
    gh += w14*__shfl(hv,14, 64);  gh += w15*__shfl(hv,15, 64);
    float val = xw + gh;
    float zv  = __shfl(val, (tid+16) & 63, 64);
    float xn_ = __shfl(xw,  (tid+32) & 63, 64);
    float gn_ = __shfl(gh,  (tid+32) & 63, 64) + bng;
    if (tid < 16){
      float r = sigmf_(val), z = sigmf_(zv);
      float n = tanhf_(xn_ + r*gn_);
      hv = (1.f - z)*n + z*hv;
      g2[((size_t)b*TS + t)*16 + tid] = hv;
    }
  }
}

// ---------------- mdense + output interleave ----------------
__global__ __launch_bounds__(256) void k_out(const float* g2, const int* targets, const float* T2,
    const float* m1w1, const float* m1w2, const float* m1b1, const float* m1b2,
    const float* m1f1, const float* m1f2,
    const float* m2w1, const float* m2w2, const float* m2b1, const float* m2b2,
    const float* m2f1, const float* m2f2, float* out)
{
  __shared__ float wA[256*17], wB[256*17], wC[256*17], wD[256*17];
  __shared__ float g2l[16*16];
  int bi = blockIdx.x; int b = bi/55; int t0 = (bi%55)*16; int c = threadIdx.x;
  for (int d = 0; d < 16; ++d){
    wA[c*17+d] = m1w1[c*16+d];  wB[c*17+d] = m1w2[c*16+d];
    wC[c*17+d] = m2w1[c*144+d]; wD[c*17+d] = m2w2[c*144+d];
  }
  { int tt = c>>4, d = c&15; g2l[c] = g2[((size_t)b*TS + t0+tt)*16 + d]; }
  __syncthreads();
  float b1a = m1b1[c], b2a = m1b2[c], f1a = m1f1[c], f2a = m1f2[c];
  float b1b = m2b1[c], b2b = m2b2[c], f1b = m2f1[c], f2b = m2f2[c];
  for (int tt = 0; tt < 16; ++tt){
    int t = t0+tt;
    float d1 = b1a, d2 = b2a, e1 = b1b, e2 = b2b;
    for (int d = 0; d < 16; ++d){
      float g = g2l[tt*16+d];
      d1 += g*wA[c*17+d]; d2 += g*wB[c*17+d];
      e1 += g*wC[c*17+d]; e2 += g*wD[c*17+d];
    }
    int v = targets[b*TT + 2*t];
    e1 += T2[v*256+c]; e2 += T2[65536 + v*256+c];
    float o1 = f1a*tanhf_(d1) + f2a*tanhf_(d2);
    float o2 = f1b*tanhf_(e1) + f2b*tanhf_(e2);
    size_t base = ((size_t)b*TS + t)*2*256;
    out[base + c]       = o1;
    out[base + 256 + c] = o2;
  }
}

extern "C" void kernel_launch(void* const* d_in, const int* in_sizes, int n_in,
                              void* d_out, int out_size, void* d_ws, size_t ws_size,
                              hipStream_t stream) {
  const int*   in_data = (const int*)  d_in[0];
  const float* feat    = (const float*)d_in[1];
  const int*   periods = (const int*)  d_in[2];
  const int*   targets = (const int*)  d_in[3];
  const float* embp    = (const float*)d_in[4];
  const float* embs    = (const float*)d_in[5];
  const float* c1w = (const float*)d_in[6];  const float* c1b = (const float*)d_in[7];
  const float* c2w = (const float*)d_in[8];  const float* c2b = (const float*)d_in[9];
  const float* f1w = (const float*)d_in[10]; const float* f1b = (const float*)d_in[11];
  const float* f2w = (const float*)d_in[12]; const float* f2b = (const float*)d_in[13];
  const float* ga_wih = (const float*)d_in[14]; const float* ga_whh = (const float*)d_in[15];
  const float* ga_bih = (const float*)d_in[16]; const float* ga_bhh = (const float*)d_in[17];
  const float* gb_wih = (const float*)d_in[18]; const float* gb_whh = (const float*)d_in[19];
  const float* gb_bih = (const float*)d_in[20]; const float* gb_bhh = (const float*)d_in[21];
  const float* m1w1 = (const float*)d_in[22]; const float* m1w2 = (const float*)d_in[23];
  const float* m1b1 = (const float*)d_in[24]; const float* m1b2 = (const float*)d_in[25];
  const float* m1f1 = (const float*)d_in[26]; const float* m1f2 = (const float*)d_in[27];
  const float* m2w1 = (const float*)d_in[28]; const float* m2w2 = (const float*)d_in[29];
  const float* m2b1 = (const float*)d_in[30]; const float* m2b2 = (const float*)d_in[31];
  const float* m2f1 = (const float*)d_in[32]; const float* m2f2 = (const float*)d_in[33];
  float* out = (float*)d_out;

  // workspace layout (floats)
  float* GA     = (float*)d_ws;                  // 6*256*1152     = 1,769,472
  float* xWrepA = GA     + 1769472;              // 704*1152       =   811,008
  float* xWrepB = xWrepA + 811008;               // 704*48         =    33,792
  float* fbuf   = xWrepB + 33792;                // 704*128        =    90,112
  float* g2buf  = fbuf   + 90112;                // 56320*16       =   901,120
  float* T2     = g2buf  + 901120;               // 2*256*256      =   131,072
  _Float16* Wpk = (_Float16*)(T2 + 131072);      // 442,368 halves
  unsigned* pbuf = (unsigned*)(Wpk + 442368);    // 64*4*2*1152 u32 = 589,824
  // d_out dead-region scratch (k_out overwrites all of d_out at the end):
  float* pxb  = (float*)d_out;                   // 64*4*880*48 = 10,813,440 floats (43.3 MB)
  float* xwBs = (float*)d_out + 13107200;        // at 52.4 MB: 64*880*48 = 2,703,360 floats (10.8 MB)

  (void)hipMemsetAsync(pbuf, 0xFF, 589824*sizeof(unsigned), stream);
  hipLaunchKernelGGL(k_setupA, dim3(1908), dim3(256), 0, stream,
                     feat, periods, embp, c1w, c1b, c2w, c2b, f1w, f1b, f2w, f2b, fbuf,
                     ga_whh, Wpk, ga_wih, embs, GA, m2w1, m2w2, T2);
  hipLaunchKernelGGL(k_setupB, dim3(82), dim3(256), 0, stream,
                     ga_wih, fbuf, ga_bih, ga_bhh, xWrepA,
                     gb_wih, gb_bih, gb_bhh, xWrepB);
  hipLaunchKernelGGL(k_scanA14, dim3(256), dim3(768), 0, stream,
                     in_data, GA, xWrepA, (const uint4*)Wpk, ga_bhh,
                     gb_wih, pbuf, pxb);
  hipLaunchKernelGGL(k_sumB, dim3(64*JREP), dim3(256), 0, stream, pxb, xWrepB, xwBs);
  hipLaunchKernelGGL(k_scanB, dim3(64), dim3(64), 0, stream,
                     xwBs, gb_whh, gb_bhh, g2buf);
  hipLaunchKernelGGL(k_out, dim3(64*55), dim3(256), 0, stream,
                     g2buf, targets, T2, m1w1, m1w2, m1b1, m1b2, m1f1, m1f2,
                     m2w1, m2w2, m2b1, m2b2, m2f1, m2f2, out);
}

// Round 16
// 3369.484 us; speedup vs baseline: 2.7804x; 1.0084x over previous
//
#include <hip/hip_runtime.h>
#include <hip/hip_bf16.h>
#include <hip/hip_fp16.h>

#define NF    15
#define NBF   20
#define TT    1760
#define TS    880
#define EP    64
#define ES    128
#define DF    128
#define H1    384
#define G3    1152
#define INA   896
#define JREP  11

typedef _Float16 h2v __attribute__((ext_vector_type(2)));
typedef unsigned long long u64;

__device__ __forceinline__ float sigmf_(float x){ return 1.0f/(1.0f + __expf(-x)); }
__device__ __forceinline__ float tanhf_(float x){ return 2.0f/(1.0f + __expf(-2.0f*x)) - 1.0f; }
__device__ __forceinline__ h2v bc_h2(unsigned u){ return __builtin_bit_cast(h2v, u); }
__device__ __forceinline__ float fdot2_(h2v a, h2v b, float c){
#if __has_builtin(__builtin_amdgcn_fdot2)
  return __builtin_amdgcn_fdot2(a, b, c, false);
#else
  return c + (float)a[0]*(float)b[0] + (float)a[1]*(float)b[1];
#endif
}
__device__ __forceinline__ unsigned pk2_(float a, float b){
#if __has_builtin(__builtin_amdgcn_cvt_pkrtz)
  return __builtin_bit_cast(unsigned, __builtin_amdgcn_cvt_pkrtz(a, b));
#else
  unsigned lo = (unsigned)__builtin_bit_cast(unsigned short, (_Float16)a);
  unsigned hi = (unsigned)__builtin_bit_cast(unsigned short, (_Float16)b);
  return lo | (hi << 16);
#endif
}
__device__ __forceinline__ void bar_lgkm(){
  asm volatile("s_waitcnt lgkmcnt(0)" ::: "memory");
  __builtin_amdgcn_s_barrier();
  __builtin_amdgcn_sched_barrier(0);
}

// ============ fused setup A: frame(0..63) | wpack5(64..1791) | tables(1792..1899) | t2(1900..1907)
__global__ __launch_bounds__(256) void k_setupA(const float* feat, const int* periods, const float* embp,
   const float* c1w, const float* c1b, const float* c2w, const float* c2b,
   const float* f1w, const float* f1b, const float* f2w, const float* f2b, float* fout,
   const float* whh, _Float16* wpk,
   const float* wih, const float* emb, float* GA,
   const float* m2w1, const float* m2w2, float* T2)
{
  __shared__ float sh[8256];
  const int bi = blockIdx.x, tid = threadIdx.x;
  if (bi < 64){
    float* cat = sh;            // 15*84 = 1260
    float* x1  = sh + 1260;     // 13*128 = 1664
    float* x2  = sh + 2924;     // 11*128 = 1408
    int b = bi;
    for (int idx = tid; idx < NF*84; idx += 256){
      int j = idx/84, c = idx%84;
      cat[idx] = (c < NBF) ? feat[(b*NF+j)*NBF + c]
                           : embp[periods[b*NF+j]*EP + (c-NBF)];
    }
    __syncthreads();
    int o = tid;
    if (o < DF){
      for (int p = 0; p < 13; ++p){
        float acc = c1b[o];
        for (int kk = 0; kk < 3; ++kk)
          for (int c = 0; c < 84; ++c)
            acc += cat[(p+kk)*84 + c] * c1w[(o*84+c)*3+kk];
        x1[p*DF+o] = tanhf_(acc);
      }
    }
    __syncthreads();
    if (o < DF){
      for (int p = 0; p < JREP; ++p){
        float acc = c2b[o];
        for (int kk = 0; kk < 3; ++kk)
          for (int c = 0; c < DF; ++c)
            acc += x1[(p+kk)*DF+c] * c2w[(o*DF+c)*3+kk];
        x2[p*DF+o] = tanhf_(acc);
      }
    }
    __syncthreads();
    if (o < DF){
      for (int p = 0; p < JREP; ++p){
        float acc = f1b[o];
        for (int c = 0; c < DF; ++c) acc += x2[p*DF+c]*f1w[o*DF+c];
        x1[p*DF+o] = tanhf_(acc);
      }
    }
    __syncthreads();
    if (o < DF){
      for (int p = 0; p < JREP; ++p){
        float acc = f2b[o];
        for (int c = 0; c < DF; ++c) acc += x1[p*DF+c]*f2w[o*DF+c];
        fout[(b*JREP+p)*DF+o] = tanhf_(acc);
      }
    }
  } else if (bi < 1792){
    int o = (bi-64)*256 + tid;                   // < 442368
    int hu = o & 1;
    int c  = (o >> 1) & 3;
    int idx = o >> 3;
    int t768 = idx % 768;
    int n    = (idx / 768) % 18;
    int hf   = idx / (768*18);
    int i = t768 % 384, u = t768 / 384;
    int gd = n*4 + c;
    int m = gd / 12, dc = gd % 12;
    int pos  = (dc % 2) + 2*(dc / 6);
    int gate = (dc % 6) >> 1;
    int j = hf*96 + u*48 + (4*m + pos)*2 + hu;
    wpk[o] = (_Float16)whh[(gate*H1 + i)*H1 + j];
  } else if (bi < 1900){
    float* Wl = sh;
    int bb = bi - 1792;
    int k = bb/18, g0 = (bb%18)*64;
    for (int idx = tid; idx < 64*128; idx += 256){
      int gg = idx>>7, c = idx&127;
      Wl[gg*129+c] = wih[(size_t)(g0+gg)*INA + k*128 + c];
    }
    __syncthreads();
    int vv = tid>>6, gg = tid&63;
    for (int v = vv; v < 256; v += 4){
      const float* e = emb + (size_t)v*ES;
      float acc = 0.f;
      for (int c = 0; c < 128; ++c) acc += e[c]*Wl[gg*129+c];
      GA[(size_t)(k*256+v)*G3 + g0+gg] = acc;
    }
  } else {
    float* Wl = sh;
    int bb = bi - 1900;
    int tbl = bb>>2; int c0 = (bb&3)*64;
    const float* w = tbl ? m2w2 : m2w1;
    for (int idx = tid; idx < 64*128; idx += 256){
      int cc = idx>>7, e = idx&127;
      Wl[cc*129+e] = w[(c0+cc)*144 + 16 + e];
    }
    __syncthreads();
    int vv = tid>>6, cc = tid&63;
    for (int v = vv; v < 256; v += 4){
      const float* e = emb + (size_t)v*ES;
      float acc = 0.f;
      for (int c = 0; c < 128; ++c) acc += e[c]*Wl[cc*129+c];
      T2[tbl*65536 + v*256 + c0+cc] = acc;
    }
  }
}

// ============ fused setup B: xwrepA(0..17) | xwrepB(18..81)
__global__ __launch_bounds__(256) void k_setupB(const float* wihA, const float* f,
        const float* bihA, const float* bhhA, float* xwA,
        const float* wihB, const float* bihB, const float* bhhB, float* xwB)
{
  __shared__ float Wl[64*129];
  const int bi = blockIdx.x, tid = threadIdx.x;
  if (bi < 18){
    int g0 = bi*64;
    for (int idx = tid; idx < 64*128; idx += 256){
      int gg = idx>>7, c = idx&127;
      Wl[gg*129+c] = wihA[(size_t)(g0+gg)*INA + 768 + c];
    }
    __syncthreads();
    int vv = tid>>6, gg = tid&63; int g = g0+gg;
    float badd = bihA[g] + (g < 768 ? bhhA[g] : 0.f);
    for (int row = vv; row < 64*JREP; row += 4){
      const float* fr = f + (size_t)row*DF;
      float acc = badd;
      for (int c = 0; c < 128; ++c) acc += fr[c]*Wl[gg*129+c];
      xwA[(size_t)row*G3 + g] = acc;
    }
  } else {
    int b = bi - 18;
    for (int idx = tid; idx < 48*128; idx += 256){
      int r = idx>>7, c = idx&127;
      Wl[r*129+c] = wihB[r*512 + 384 + c];
    }
    __syncthreads();
    for (int idx = tid; idx < JREP*48; idx += 256){
      int j = idx/48, r = idx%48;
      const float* fr = f + (size_t)(b*JREP+j)*DF;
      float acc = bihB[r] + (r < 32 ? bhhB[r] : 0.f);
      for (int c = 0; c < 128; ++c) acc += fr[c]*Wl[r*129+c];
      xwB[(size_t)(b*JREP+j)*48 + r] = acc;
    }
  }
}

// ---------------- GRU-A scan v14: R13 + in-scan xwB partials ----------------
#define LD18(n) uint4 d##n = wsrc[(size_t)(n)*768];
#define Q2(A,B,C, q2) { \
  h2v hA = hh[jb2 + (q2)*2],     hB = hh[jb2 + (q2)*2 + 1]; \
  ar = fdot2_(hA, bc_h2(A.x), ar); ar = fdot2_(hB, bc_h2(A.y), ar); \
  az = fdot2_(hA, bc_h2(A.z), az); az = fdot2_(hB, bc_h2(A.w), az); \
  an = fdot2_(hA, bc_h2(B.x), an); an = fdot2_(hB, bc_h2(B.y), an); \
  h2v hC = hh[jb2 + (q2)*2 + 2], hD = hh[jb2 + (q2)*2 + 3]; \
  ar = fdot2_(hC, bc_h2(B.z), ar); ar = fdot2_(hD, bc_h2(B.w), ar); \
  az = fdot2_(hC, bc_h2(C.x), az); az = fdot2_(hD, bc_h2(C.y), az); \
  an = fdot2_(hC, bc_h2(C.z), an); an = fdot2_(hD, bc_h2(C.w), an); }
#define DOTS12 \
  Q2(d0,d1,d2,0) Q2(d3,d4,d5,2) Q2(d6,d7,d8,4) \
  Q2(d9,d10,d11,6) Q2(d12,d13,d14,8) Q2(d15,d16,d17,10)

#define PL2(na, nb_, p) { u64 w2 = __hip_atomic_load((const u64*)(p), __ATOMIC_RELAXED, __HIP_MEMORY_SCOPE_AGENT); \
  rv##na = (unsigned)w2; rv##nb_ = (unsigned)(w2 >> 32); \
  ok &= ((rv##na & 1023u) == tg) & ((rv##nb_ & 1023u) == tg); }

__global__ __launch_bounds__(768, 3) void k_scanA14(const int* __restrict__ in_data,
        const float* __restrict__ GA, const float* __restrict__ xwA,
        const uint4* __restrict__ wpk, const float* __restrict__ bhh,
        const float* __restrict__ wihB, unsigned* pbuf, float* __restrict__ pxb)
{
  __shared__ __align__(16) unsigned h16u[48];     // own j-quarter h(t-1): 96 rows = 48 u32
  __shared__ __align__(8)  float pg[3][2][384];   // own-quarter partials [gate][u][out-row]
  __shared__ __align__(8)  float xwb[2][G3];      // xW double buffer
  __shared__ __align__(8)  unsigned wlB[48*49];   // gruB wih quarter slice, f16 pairs (padded)
  __shared__ int indr[2][8];
  const int P = blockIdx.x;
  const int b = P & 63, hf = P >> 6;
  const int tid = threadIdx.x;
  const int i  = tid % 384;
  const int u  = tid / 384;
  const int jb2 = u * 24;
  const int* ind_b = in_data + (size_t)b*TT*3;

  const uint4* wsrc = wpk + (size_t)(hf*18)*768 + tid;
  LD18(0) LD18(1) LD18(2) LD18(3) LD18(4) LD18(5) LD18(6) LD18(7) LD18(8)
  LD18(9) LD18(10) LD18(11) LD18(12) LD18(13) LD18(14) LD18(15) LD18(16) LD18(17)

  for (int idx = tid; idx < 48*48; idx += 768){
    int r = idx/48, k = idx%48;
    wlB[r*49+k] = pk2_(wihB[r*512 + hf*96 + 2*k], wihB[r*512 + hf*96 + 2*k + 1]);
  }

  const bool isGat = (tid < 576);
  const int  c0 = 2*tid, c1 = 2*tid + 1;
  const bool isPub = (tid >= 96 && tid < 672);
  const int  po0 = 2*(tid - 96);
  const bool isPxb = (tid >= 48 && tid < 96);
  float* pxbBase = pxb + (size_t)(b*4 + hf)*TS*48 + (tid - 48);

  float hreg0 = 0.f, hreg1 = 0.f, bn0 = 0.f, bn1 = 0.f;
  if (tid < 48){
    bn0 = bhh[768 + hf*96 + 2*tid];
    bn1 = bhh[768 + hf*96 + 2*tid + 1];
    h16u[tid] = 0u;
  }
  if (isGat){
    float s0 = xwA[(size_t)(b*JREP)*G3 + c0];
    float s1 = xwA[(size_t)(b*JREP)*G3 + c1];
    #pragma unroll
    for (int k2 = 0; k2 < 6; ++k2){
      int v = ind_b[k2];
      s0 += GA[((size_t)k2*256 + v)*G3 + c0];
      s1 += GA[((size_t)k2*256 + v)*G3 + c1];
    }
    xwb[0][c0] = s0; xwb[0][c1] = s1;
  }
  if (tid >= 576 && tid < 582) indr[1][tid-576] = ind_b[6 + (tid-576)];

  unsigned* pbo = pbuf + ((size_t)(b*4 + hf)*2)*G3;
  const int pf1 = (hf+1)&3, pf2 = (hf+2)&3, pf3 = (hf+3)&3;
  const unsigned* pb1 = pbuf + ((size_t)(b*4 + pf1)*2)*G3 + hf*96 + 2*(tid<48?tid:0);
  const unsigned* pb2 = pbuf + ((size_t)(b*4 + pf2)*2)*G3 + hf*96 + 2*(tid<48?tid:0);
  const unsigned* pb3 = pbuf + ((size_t)(b*4 + pf3)*2)*G3 + hf*96 + 2*(tid<48?tid:0);
  const h2v* hh = (const h2v*)h16u;
  __syncthreads();

  for (int t = 0; t < TS; ++t){
    const int nb = t & 1;
    const int tp = t + 1;
    float ga0=0.f,ga1=0.f,ga2=0.f,ga3=0.f,ga4=0.f,ga5=0.f,gx0=0.f;
    float gb0=0.f,gb1=0.f,gb2=0.f,gb3=0.f,gb4=0.f,gb5=0.f,gx1=0.f;
    if (tp < TS && isGat){
      int v0=indr[tp&1][0], v1=indr[tp&1][1], v2=indr[tp&1][2];
      int v3=indr[tp&1][3], v4=indr[tp&1][4], v5=indr[tp&1][5];
      const float* xwr = xwA + ((size_t)(b*JREP) + tp/80)*G3;
      ga0 = GA[((size_t)0*256 + v0)*G3 + c0]; gb0 = GA[((size_t)0*256 + v0)*G3 + c1];
      ga1 = GA[((size_t)1*256 + v1)*G3 + c0]; gb1 = GA[((size_t)1*256 + v1)*G3 + c1];
      ga2 = GA[((size_t)2*256 + v2)*G3 + c0]; gb2 = GA[((size_t)2*256 + v2)*G3 + c1];
      ga3 = GA[((size_t)3*256 + v3)*G3 + c0]; gb3 = GA[((size_t)3*256 + v3)*G3 + c1];
      ga4 = GA[((size_t)4*256 + v4)*G3 + c0]; gb4 = GA[((size_t)4*256 + v4)*G3 + c1];
      ga5 = GA[((size_t)5*256 + v5)*G3 + c0]; gb5 = GA[((size_t)5*256 + v5)*G3 + c1];
      gx0 = xwr[c0]; gx1 = xwr[c1];
    }
    int iv = 0;
    const int stg = t + 2;
    const bool doStg = (tid >= 576 && tid < 582 && stg < TS);
    if (doStg) iv = ind_b[6*stg + (tid-576)];
    float ar=0.f, az=0.f, an=0.f;
    DOTS12
    pg[0][u][i] = ar; pg[1][u][i] = az; pg[2][u][i] = an;
    if (isPxb && t > 0){
      int r = tid - 48;
      float acc = 0.f;
      #pragma unroll 8
      for (int k = 0; k < 48; ++k) acc = fdot2_(hh[k], bc_h2(wlB[r*49+k]), acc);
      pxbBase[(size_t)(t-1)*48] = acc;
    }
    if (tp < TS && isGat){
      xwb[tp&1][c0] = ga0+ga1+ga2+ga3+ga4+ga5+gx0;
      xwb[tp&1][c1] = gb0+gb1+gb2+gb3+gb4+gb5+gx1;
    }
    if (doStg) indr[t&1][tid-576] = iv;
    bar_lgkm();
    if (isPub){
      int g = po0/384, ii = po0 - g*384;
      float2 p0 = *(const float2*)&pg[g][0][ii];
      float2 p1 = *(const float2*)&pg[g][1][ii];
      float v0 = p0.x + p1.x, v1 = p0.y + p1.y;
      unsigned tw0 = (__builtin_bit_cast(unsigned, v0) & 0xFFFFFC00u) | (unsigned)(t & 1023);
      unsigned tw1 = (__builtin_bit_cast(unsigned, v1) & 0xFFFFFC00u) | (unsigned)(t & 1023);
      unsigned* dst = pbo + (size_t)nb*G3 + po0;
      __hip_atomic_store(dst,     tw0, __ATOMIC_RELAXED, __HIP_MEMORY_SCOPE_AGENT);
      __hip_atomic_store(dst + 1, tw1, __ATOMIC_RELAXED, __HIP_MEMORY_SCOPE_AGENT);
    } else if (tid < 48){
      const unsigned tg = (unsigned)t & 1023u;
      const unsigned* q1 = pb1 + (size_t)nb*G3;
      const unsigned* q2 = pb2 + (size_t)nb*G3;
      const unsigned* q3 = pb3 + (size_t)nb*G3;
      unsigned rv0,rv1,rv2,rv3,rv4,rv5,rv6,rv7,rv8;
      unsigned rv9,rv10,rv11,rv12,rv13,rv14,rv15,rv16,rv17;
      bool ok;
      do {
        ok = true;
        PL2(0,1,   q1+0) PL2(2,3,   q1+384) PL2(4,5,   q1+768)
        PL2(6,7,   q2+0) PL2(8,9,   q2+384) PL2(10,11, q2+768)
        PL2(12,13, q3+0) PL2(14,15, q3+384) PL2(16,17, q3+768)
        if (!ok) __builtin_amdgcn_s_sleep(1);
      } while (!ok);
      __builtin_amdgcn_sched_barrier(0);
      #define FV(n) __builtin_bit_cast(float, rv##n & 0xFFFFFC00u)
      int i0 = hf*96 + 2*tid;
      float2 o0 = *(const float2*)&pg[0][0][i0];  float2 o0b = *(const float2*)&pg[0][1][i0];
      float2 o1 = *(const float2*)&pg[1][0][i0];  float2 o1b = *(const float2*)&pg[1][1][i0];
      float2 o2 = *(const float2*)&pg[2][0][i0];  float2 o2b = *(const float2*)&pg[2][1][i0];
      float2 xr = *(const float2*)&xwb[nb][i0];
      float2 xz = *(const float2*)&xwb[nb][384 + i0];
      float2 xn = *(const float2*)&xwb[nb][768 + i0];
      float R0 = o0.x + o0b.x + FV(0)  + FV(6)  + FV(12) + xr.x;
      float R1 = o0.y + o0b.y + FV(1)  + FV(7)  + FV(13) + xr.y;
      float Z0 = o1.x + o1b.x + FV(2)  + FV(8)  + FV(14) + xz.x;
      float Z1 = o1.y + o1b.y + FV(3)  + FV(9)  + FV(15) + xz.y;
      float G0 = o2.x + o2b.x + FV(4)  + FV(10) + FV(16) + bn0;
      float G1 = o2.y + o2b.y + FV(5)  + FV(11) + FV(17) + bn1;
      #undef FV
      float rr0 = sigmf_(R0), zz0 = sigmf_(Z0);
      float nn0 = tanhf_(xn.x + rr0*G0);
      float h0 = (1.f - zz0)*nn0 + zz0*hreg0; hreg0 = h0;
      float rr1 = sigmf_(R1), zz1 = sigmf_(Z1);
      float nn1 = tanhf_(xn.y + rr1*G1);
      float h1 = (1.f - zz1)*nn1 + zz1*hreg1; hreg1 = h1;
      h16u[tid] = pk2_(h0, h1);
    }
    bar_lgkm();
  }
  if (isPxb){
    int r = tid - 48;
    float acc = 0.f;
    #pragma unroll 8
    for (int k = 0; k < 48; ++k) acc = fdot2_(hh[k], bc_h2(wlB[r*49+k]), acc);
    pxbBase[(size_t)(TS-1)*48] = acc;
  }
}

// ---------------- sum partials: xwBs[b][t][48] = sum_q pxb[q] + xwrepB ----------------
__global__ __launch_bounds__(256) void k_sumB(const float* pxb, const float* xwrB, float* xwBs){
  int bi = blockIdx.x;            // 64*11 = 704 blocks: (b, frame j)
  int b = bi / JREP, j = bi % JREP;
  int tid = threadIdx.x;
  const float* p0 = pxb + (size_t)(b*4+0)*TS*48 + (size_t)j*80*48;
  const float* p1 = pxb + (size_t)(b*4+1)*TS*48 + (size_t)j*80*48;
  const float* p2 = pxb + (size_t)(b*4+2)*TS*48 + (size_t)j*80*48;
  const float* p3 = pxb + (size_t)(b*4+3)*TS*48 + (size_t)j*80*48;
  const float* xr = xwrB + (size_t)(b*JREP + j)*48;
  float* dst = xwBs + (size_t)b*TS*48 + (size_t)j*80*48;
  for (int idx = tid; idx < 80*48; idx += 256){
    int r = idx % 48;
    dst[idx] = p0[idx] + p1[idx] + p2[idx] + p3[idx] + xr[r];
  }
}

// ---------------- GRU-B scan: single-wave shuffle, 8-deep prefetch of single stream ------------
__global__ __launch_bounds__(64) void k_scanB(const float* xwBs, const float* whh,
                                              const float* bhh, float* g2){
  int b = blockIdx.x, tid = threadIdx.x;
  float w0=0,w1=0,w2=0,w3=0,w4=0,w5=0,w6=0,w7=0;
  float w8=0,w9=0,w10=0,w11=0,w12=0,w13=0,w14=0,w15=0;
  if (tid < 48){
    const float* wr = whh + tid*16;
    w0=wr[0];w1=wr[1];w2=wr[2];w3=wr[3];w4=wr[4];w5=wr[5];w6=wr[6];w7=wr[7];
    w8=wr[8];w9=wr[9];w10=wr[10];w11=wr[11];w12=wr[12];w13=wr[13];w14=wr[14];w15=wr[15];
  }
  float bng = (tid < 16) ? bhh[32 + tid] : 0.f;
  const float* src = xwBs + (size_t)b*TS*48 + tid;
  float hv = 0.f;
  float f0=0,f1=0,f2=0,f3=0,f4=0,f5=0,f6=0,f7=0;
  if (tid < 48){
    f0 = src[0*48]; f1 = src[1*48]; f2 = src[2*48]; f3 = src[3*48];
    f4 = src[4*48]; f5 = src[5*48]; f6 = src[6*48]; f7 = src[7*48];
  }
  for (int t = 0; t < TS; ++t){
    float xw = f0;
    f0=f1; f1=f2; f2=f3; f3=f4; f4=f5; f5=f6; f6=f7;
    if (t+8 < TS && tid < 48) f7 = src[(size_t)(t+8)*48];
    float gh = 0.f;
    gh += w0 *__shfl(hv, 0, 64);  gh += w1 *__shfl(hv, 1, 64);
    gh += w2 *__shfl(hv, 2, 64);  gh += w3 *__shfl(hv, 3, 64);
    gh += w4 *__shfl(hv, 4, 64);  gh += w5 *__shfl(hv, 5, 64);
    gh += w6 *__shfl(hv, 6, 64);  gh += w7 *__shfl(hv, 7, 64);
    gh += w8 *__shfl(hv, 8, 64);  gh += w9 *__shfl(hv, 9, 64);
    gh += w10*__shfl(hv,10, 64);  gh += w11*__shfl(hv,11, 64);
    gh += w12*__shfl(hv,12, 64);  gh += w13*__shfl(hv,13, 64);
    gh += w14*__shfl(hv,14, 64);  gh += w15*__shfl(hv,15, 64);
    float val = xw + gh;
    float zv  = __shfl(val, (tid+16) & 63, 64);
    float xn_ = __shfl(xw,  (tid+32) & 63, 64);
    float gn_ = __shfl(gh,  (tid+32) & 63, 64) + bng;
    if (tid < 16){
      float r = sigmf_(val), z = sigmf_(zv);
      float n = tanhf_(xn_ + r*gn_);
      hv = (1.f - z)*n + z*hv;
      g2[((size_t)b*TS + t)*16 + tid] = hv;
    }
  }
}

// ---------------- mdense + output interleave (weights in registers, minimal LDS) ----------------
__global__ __launch_bounds__(256) void k_out(const float* g2, const int* targets, const float* T2,
    const float* m1w1, const float* m1w2, const float* m1b1, const float* m1b2,
    const float* m1f1, const float* m1f2,
    const float* m2w1, const float* m2w2, const float* m2b1, const float* m2b2,
    const float* m2f1, const float* m2f2, float* out)
{
  __shared__ float g2l[16*16];
  int bi = blockIdx.x; int b = bi/55; int t0 = (bi%55)*16; int c = threadIdx.x;
  float wa[16], wb[16], wc[16], wd[16];
  #pragma unroll
  for (int d = 0; d < 16; ++d){
    wa[d] = m1w1[c*16+d];  wb[d] = m1w2[c*16+d];
    wc[d] = m2w1[c*144+d]; wd[d] = m2w2[c*144+d];
  }
  { int tt = c>>4, d = c&15; g2l[c] = g2[((size_t)b*TS + t0+tt)*16 + d]; }
  __syncthreads();
  float b1a = m1b1[c], b2a = m1b2[c], f1a = m1f1[c], f2a = m1f2[c];
  float b1b = m2b1[c], b2b = m2b2[c], f1b = m2f1[c], f2b = m2f2[c];
  for (int tt = 0; tt < 16; ++tt){
    int t = t0+tt;
    float d1 = b1a, d2 = b2a, e1 = b1b, e2 = b2b;
    #pragma unroll
    for (int d = 0; d < 16; ++d){
      float g = g2l[tt*16+d];
      d1 += g*wa[d]; d2 += g*wb[d];
      e1 += g*wc[d]; e2 += g*wd[d];
    }
    int v = targets[b*TT + 2*t];
    e1 += T2[v*256+c]; e2 += T2[65536 + v*256+c];
    float o1 = f1a*tanhf_(d1) + f2a*tanhf_(d2);
    float o2 = f1b*tanhf_(e1) + f2b*tanhf_(e2);
    size_t base = ((size_t)b*TS + t)*2*256;
    out[base + c]       = o1;
    out[base + 256 + c] = o2;
  }
}

extern "C" void kernel_launch(void* const* d_in, const int* in_sizes, int n_in,
                              void* d_out, int out_size, void* d_ws, size_t ws_size,
                              hipStream_t stream) {
  const int*   in_data = (const int*)  d_in[0];
  const float* feat    = (const float*)d_in[1];
  const int*   periods = (const int*)  d_in[2];
  const int*   targets = (const int*)  d_in[3];
  const float* embp    = (const float*)d_in[4];
  const float* embs    = (const float*)d_in[5];
  const float* c1w = (const float*)d_in[6];  const float* c1b = (const float*)d_in[7];
  const float* c2w = (const float*)d_in[8];  const float* c2b = (const float*)d_in[9];
  const float* f1w = (const float*)d_in[10]; const float* f1b = (const float*)d_in[11];
  const float* f2w = (const float*)d_in[12]; const float* f2b = (const float*)d_in[13];
  const float* ga_wih = (const float*)d_in[14]; const float* ga_whh = (const float*)d_in[15];
  const float* ga_bih = (const float*)d_in[16]; const float* ga_bhh = (const float*)d_in[17];
  const float* gb_wih = (const float*)d_in[18]; const float* gb_whh = (const float*)d_in[19];
  const float* gb_bih = (const float*)d_in[20]; const float* gb_bhh = (const float*)d_in[21];
  const float* m1w1 = (const float*)d_in[22]; const float* m1w2 = (const float*)d_in[23];
  const float* m1b1 = (const float*)d_in[24]; const float* m1b2 = (const float*)d_in[25];
  const float* m1f1 = (const float*)d_in[26]; const float* m1f2 = (const float*)d_in[27];
  const float* m2w1 = (const float*)d_in[28]; const float* m2w2 = (const float*)d_in[29];
  const float* m2b1 = (const float*)d_in[30]; const float* m2b2 = (const float*)d_in[31];
  const float* m2f1 = (const float*)d_in[32]; const float* m2f2 = (const float*)d_in[33];
  float* out = (float*)d_out;

  // workspace layout (floats)
  float* GA     = (float*)d_ws;                  // 6*256*1152     = 1,769,472
  float* xWrepA = GA     + 1769472;              // 704*1152       =   811,008
  float* xWrepB = xWrepA + 811008;               // 704*48         =    33,792
  float* fbuf   = xWrepB + 33792;                // 704*128        =    90,112
  float* g2buf  = fbuf   + 90112;                // 56320*16       =   901,120
  float* T2     = g2buf  + 901120;               // 2*256*256      =   131,072
  _Float16* Wpk = (_Float16*)(T2 + 131072);      // 442,368 halves
  unsigned* pbuf = (unsigned*)(Wpk + 442368);    // 64*4*2*1152 u32 = 589,824
  // d_out dead-region scratch (k_out overwrites all of d_out at the end):
  float* pxb  = (float*)d_out;                   // 64*4*880*48 = 10,813,440 floats (43.3 MB)
  float* xwBs = (float*)d_out + 13107200;        // at 52.4 MB: 64*880*48 = 2,703,360 floats (10.8 MB)

  (void)hipMemsetAsync(pbuf, 0xFF, 589824*sizeof(unsigned), stream);
  hipLaunchKernelGGL(k_setupA, dim3(1908), dim3(256), 0, stream,
                     feat, periods, embp, c1w, c1b, c2w, c2b, f1w, f1b, f2w, f2b, fbuf,
                     ga_whh, Wpk, ga_wih, embs, GA, m2w1, m2w2, T2);
  hipLaunchKernelGGL(k_setupB, dim3(82), dim3(256), 0, stream,
                     ga_wih, fbuf, ga_bih, ga_bhh, xWrepA,
                     gb_wih, gb_bih, gb_bhh, xWrepB);
  hipLaunchKernelGGL(k_scanA14, dim3(256), dim3(768), 0, stream,
                     in_data, GA, xWrepA, (const uint4*)Wpk, ga_bhh,
                     gb_wih, pbuf, pxb);
  hipLaunchKernelGGL(k_sumB, dim3(64*JREP), dim3(256), 0, stream, pxb, xWrepB, xwBs);
  hipLaunchKernelGGL(k_scanB, dim3(64), dim3(64), 0, stream,
                     xwBs, gb_whh, gb_bhh, g2buf);
  hipLaunchKernelGGL(k_out, dim3(64*55), dim3(256), 0, stream,
                     g2buf, targets, T2, m1w1, m1w2, m1b1, m1b2, m1f1, m1f2,
                     m2w1, m2w2, m2b1, m2b2, m2f1, m2f2, out);
}